// Round 3
// baseline (8844.477 us; speedup 1.0000x reference)
//
#include <hip/hip_runtime.h>
#include <math.h>

// Problem constants
#define SEQL 128
#define NB   32
#define EMBD 300
#define HH   400      // hidden per direction
#define G4   1600     // 4*HH
#define FF   512
#define NLAB 9
#define NBLK 200      // persistent LSTM blocks: 2 dirs x 100 slices (4 hidden units each)

// ---------------- workspace layout (bytes) ----------------
// x [4096][300] f32 at 0 (4,915,200) — dead after input GEMMs; hbuf/bar overlay it after.
static const size_t OFF_X    = 0;
static const size_t OFF_HBUF = 0;          // h double-buffer [2][2][400][32] f64 (819,200) — live only inside k_lstm2
static const size_t OFF_BAR  = 1048576;    // barrier counters (64 B) — inside dead x region
static const size_t OFF_XW   = 5242880;    // XWt [2][128][1600][32] f32 (52,428,800) dead after LSTM
static const size_t OFF_ENC  = 62914560;   // enc [4096][800] f32 (13,107,200) dead after proj GEMMs
static const size_t OFF_U    = 0;          // U [4096][9][516] f32 (76,087,296) overlays everything above (post-LSTM)
static const size_t OFF_X1   = 76087296;   // x1 [4096][516] (513 used) (8,454,144)
static const size_t OFF_Y1T  = 84541440;   // y1T [32][513][128] (8,404,992)
static const size_t OFF_KEYS = 92946432;   // keys u64 [32][16384] (4,194,304)
static const size_t OFF_WBP  = 97140736;   // Wb padded [9][513][516] (9,529,488)

// ---------------- embedding gather ----------------
__global__ __launch_bounds__(256) void k_gather(const int* __restrict__ wi,
                                                const float* __restrict__ emb,
                                                float* __restrict__ x) {
  int m = blockIdx.x;                 // 0..4095 = b*128 + l
  int idx = wi[m];
  const float* src = emb + (size_t)idx * EMBD;
  float* dst = x + (size_t)m * EMBD;
  for (int e = threadIdx.x; e < EMBD; e += 256) dst[e] = src[e];
}

// ---------------- W_biaffine pad to stride 516 ----------------
__global__ __launch_bounds__(256) void k_wbpad(const float* __restrict__ wbi,
                                               float* __restrict__ wbp) {
  int tid = blockIdx.x * 256 + threadIdx.x;
  const int PER = 513 * 516;
  if (tid >= 9 * PER) return;
  int o = tid / PER;
  int r = tid - o * PER;
  int i = r / 516;
  int j = r - i * 516;
  wbp[tid] = (j < 513) ? wbi[(size_t)o * 513 * 513 + (size_t)i * 513 + j] : 0.f;
}

// ---------------- ones columns ----------------
__global__ __launch_bounds__(256) void k_ones(float* __restrict__ x1, float* __restrict__ y1T) {
  int tid = blockIdx.x * 256 + threadIdx.x;
  if (tid < 4096) {
    x1[(size_t)tid * 516 + 512] = 1.f;
  } else if (tid < 8192) {
    int r = tid - 4096;
    int bb = r >> 7, y = r & 127;
    y1T[((size_t)bb * 513 + 512) * 128 + y] = 1.f;
  }
}

// ---------------- tiled GEMM, f64 accumulate, C = A * W^T (+b1+b2)
// mode 0: normal store; mode 1: y1T transposed store; mode 2: XWt store [l][n][b]
__global__ __launch_bounds__(256) void k_gemm_nt(const float* __restrict__ A, int lda,
                                                 const float* __restrict__ W, int ldw,
                                                 const float* __restrict__ bias1,
                                                 const float* __restrict__ bias2,
                                                 float* __restrict__ C, int ldc,
                                                 int M, int N, int K, int mode) {
  __shared__ __align__(16) double As[16][68];
  __shared__ __align__(16) double Bs[16][68];
  int t = threadIdx.x;
  int m0 = blockIdx.x * 64, n0 = blockIdx.y * 64;
  int tm = t & 15, tn = t >> 4;
  int ar = t >> 2, akq = t & 3;
  double acc[4][4];
#pragma unroll
  for (int r = 0; r < 4; ++r)
#pragma unroll
    for (int c = 0; c < 4; ++c) acc[r][c] = 0.0;

  for (int k0 = 0; k0 < K; k0 += 16) {
    {
      const float* ap = A + (size_t)(m0 + ar) * lda + k0 + 4 * akq;
      float v0, v1, v2, v3;
      if (k0 + 4 * akq + 4 <= K) {
        float4 f = *(const float4*)ap; v0 = f.x; v1 = f.y; v2 = f.z; v3 = f.w;
      } else {
        v0 = (k0 + 4 * akq + 0 < K) ? ap[0] : 0.f;
        v1 = (k0 + 4 * akq + 1 < K) ? ap[1] : 0.f;
        v2 = (k0 + 4 * akq + 2 < K) ? ap[2] : 0.f;
        v3 = (k0 + 4 * akq + 3 < K) ? ap[3] : 0.f;
      }
      As[4 * akq + 0][ar] = (double)v0; As[4 * akq + 1][ar] = (double)v1;
      As[4 * akq + 2][ar] = (double)v2; As[4 * akq + 3][ar] = (double)v3;
    }
    {
      int nr = n0 + ar;
      float v0 = 0.f, v1 = 0.f, v2 = 0.f, v3 = 0.f;
      if (nr < N) {
        const float* wp = W + (size_t)nr * ldw + k0 + 4 * akq;
        if (k0 + 4 * akq + 4 <= K) {
          float4 f = *(const float4*)wp; v0 = f.x; v1 = f.y; v2 = f.z; v3 = f.w;
        } else {
          if (k0 + 4 * akq + 0 < K) v0 = wp[0];
          if (k0 + 4 * akq + 1 < K) v1 = wp[1];
          if (k0 + 4 * akq + 2 < K) v2 = wp[2];
          if (k0 + 4 * akq + 3 < K) v3 = wp[3];
        }
      }
      Bs[4 * akq + 0][ar] = (double)v0; Bs[4 * akq + 1][ar] = (double)v1;
      Bs[4 * akq + 2][ar] = (double)v2; Bs[4 * akq + 3][ar] = (double)v3;
    }
    __syncthreads();
#pragma unroll
    for (int kk = 0; kk < 16; ++kk) {
      double2 a01 = *(const double2*)&As[kk][4 * tm];
      double2 a23 = *(const double2*)&As[kk][4 * tm + 2];
      double2 b01 = *(const double2*)&Bs[kk][4 * tn];
      double2 b23 = *(const double2*)&Bs[kk][4 * tn + 2];
      double av[4] = {a01.x, a01.y, a23.x, a23.y};
      double bv[4] = {b01.x, b01.y, b23.x, b23.y};
#pragma unroll
      for (int r = 0; r < 4; ++r)
#pragma unroll
        for (int c = 0; c < 4; ++c) acc[r][c] = fma(av[r], bv[c], acc[r][c]);
    }
    __syncthreads();
  }
  double bn[4];
#pragma unroll
  for (int c = 0; c < 4; ++c) {
    int n = n0 + 4 * tn + c;
    double bv = 0.0;
    if (n < N) {
      if (bias1) bv += (double)bias1[n];
      if (bias2) bv += (double)bias2[n];
    }
    bn[c] = bv;
  }
  if (mode == 0) {
#pragma unroll
    for (int r = 0; r < 4; ++r) {
      int m = m0 + 4 * tm + r;
      float* cp = C + (size_t)m * ldc + n0 + 4 * tn;
      if (n0 + 4 * tn + 4 <= N) {
        float4 s = make_float4((float)(acc[r][0] + bn[0]), (float)(acc[r][1] + bn[1]),
                               (float)(acc[r][2] + bn[2]), (float)(acc[r][3] + bn[3]));
        *(float4*)cp = s;
      } else {
#pragma unroll
        for (int c = 0; c < 4; ++c)
          if (n0 + 4 * tn + c < N) cp[c] = (float)(acc[r][c] + bn[c]);
      }
    }
  } else if (mode == 1) {
    // transposed store into y1T[(b*513+n)*128 + y], m = b*128 + y
#pragma unroll
    for (int r = 0; r < 4; ++r) {
      int m = m0 + 4 * tm + r;
      int bb = m >> 7, y = m & 127;
#pragma unroll
      for (int c = 0; c < 4; ++c) {
        int n = n0 + 4 * tn + c;
        if (n < N) C[((size_t)bb * 513 + n) * 128 + y] = (float)(acc[r][c] + bn[c]);
      }
    }
  } else {
    // XWt store: C[(l*1600 + n)*32 + b], m = b*128 + l
#pragma unroll
    for (int r = 0; r < 4; ++r) {
      int m = m0 + 4 * tm + r;
      int bb = m >> 7, l = m & 127;
#pragma unroll
      for (int c = 0; c < 4; ++c) {
        int n = n0 + 4 * tn + c;
        if (n < N) C[((size_t)l * G4 + n) * 32 + bb] = (float)(acc[r][c] + bn[c]);
      }
    }
  }
}

// ---------------- tiled GEMM f64-acc, C(+o*516 col) = A * B (B row-major), batched over o ----------------
__global__ __launch_bounds__(256) void k_gemm_nn(const float* __restrict__ A, int lda,
                                                 const float* __restrict__ Bm, int ldb,
                                                 size_t strideB,
                                                 float* __restrict__ C, int ldc,
                                                 int M, int N, int K) {
  __shared__ __align__(16) double As[16][68];
  __shared__ __align__(16) double Bs[16][68];
  int t = threadIdx.x;
  int o = blockIdx.z;
  const float* B = Bm + (size_t)o * strideB;
  float* Cb = C + (size_t)o * 516;
  int m0 = blockIdx.x * 64, n0 = blockIdx.y * 64;
  int tm = t & 15, tn = t >> 4;
  int ar = t >> 2, akq = t & 3;
  double acc[4][4];
#pragma unroll
  for (int r = 0; r < 4; ++r)
#pragma unroll
    for (int c = 0; c < 4; ++c) acc[r][c] = 0.0;

  for (int k0 = 0; k0 < K; k0 += 16) {
    {
      const float* ap = A + (size_t)(m0 + ar) * lda + k0 + 4 * akq;
      float v0, v1, v2, v3;
      if (k0 + 4 * akq + 4 <= K) {
        float4 f = *(const float4*)ap; v0 = f.x; v1 = f.y; v2 = f.z; v3 = f.w;
      } else {
        v0 = (k0 + 4 * akq + 0 < K) ? ap[0] : 0.f;
        v1 = (k0 + 4 * akq + 1 < K) ? ap[1] : 0.f;
        v2 = (k0 + 4 * akq + 2 < K) ? ap[2] : 0.f;
        v3 = (k0 + 4 * akq + 3 < K) ? ap[3] : 0.f;
      }
      As[4 * akq + 0][ar] = (double)v0; As[4 * akq + 1][ar] = (double)v1;
      As[4 * akq + 2][ar] = (double)v2; As[4 * akq + 3][ar] = (double)v3;
    }
    {
      int kr = k0 + (t >> 4);
      int nc = n0 + 4 * (t & 15);
      float v0 = 0.f, v1 = 0.f, v2 = 0.f, v3 = 0.f;
      if (kr < K) {
        const float* bp = B + (size_t)kr * ldb + nc;
        if (nc + 4 <= N) {
          float4 f = *(const float4*)bp; v0 = f.x; v1 = f.y; v2 = f.z; v3 = f.w;
        } else {
          if (nc + 0 < N) v0 = bp[0];
          if (nc + 1 < N) v1 = bp[1];
          if (nc + 2 < N) v2 = bp[2];
          if (nc + 3 < N) v3 = bp[3];
        }
      }
      int kk = t >> 4, nq = 4 * (t & 15);
      Bs[kk][nq + 0] = (double)v0; Bs[kk][nq + 1] = (double)v1;
      Bs[kk][nq + 2] = (double)v2; Bs[kk][nq + 3] = (double)v3;
    }
    __syncthreads();
#pragma unroll
    for (int kk = 0; kk < 16; ++kk) {
      double2 a01 = *(const double2*)&As[kk][4 * tm];
      double2 a23 = *(const double2*)&As[kk][4 * tm + 2];
      double2 b01 = *(const double2*)&Bs[kk][4 * tn];
      double2 b23 = *(const double2*)&Bs[kk][4 * tn + 2];
      double av[4] = {a01.x, a01.y, a23.x, a23.y};
      double bv[4] = {b01.x, b01.y, b23.x, b23.y};
#pragma unroll
      for (int r = 0; r < 4; ++r)
#pragma unroll
        for (int c = 0; c < 4; ++c) acc[r][c] = fma(av[r], bv[c], acc[r][c]);
    }
    __syncthreads();
  }
#pragma unroll
  for (int r = 0; r < 4; ++r) {
    int m = m0 + 4 * tm + r;
    float* cp = Cb + (size_t)m * ldc + n0 + 4 * tn;
    if (n0 + 4 * tn + 4 <= N) {
      *(float4*)cp = make_float4((float)acc[r][0], (float)acc[r][1],
                                 (float)acc[r][2], (float)acc[r][3]);
    } else {
#pragma unroll
      for (int c = 0; c < 4; ++c)
        if (n0 + 4 * tn + c < N) cp[c] = (float)acc[r][c];
    }
  }
}

// ---------------- grid barrier (all NBLK blocks co-resident: 200 <= 256 CUs) ----------------
__device__ __forceinline__ void gridbar(unsigned* bar, unsigned nb, unsigned phase) {
  __syncthreads();
  if (threadIdx.x == 0) {
    __threadfence();  // publish prior global writes (device scope)
    unsigned arrived = __hip_atomic_fetch_add(&bar[0], 1u, __ATOMIC_ACQ_REL,
                                              __HIP_MEMORY_SCOPE_AGENT) + 1u;
    if (arrived == nb) {
      __hip_atomic_store(&bar[0], 0u, __ATOMIC_RELAXED, __HIP_MEMORY_SCOPE_AGENT);
      __hip_atomic_fetch_add(&bar[1], 1u, __ATOMIC_ACQ_REL, __HIP_MEMORY_SCOPE_AGENT);
    } else {
      while (__hip_atomic_load(&bar[1], __ATOMIC_ACQUIRE, __HIP_MEMORY_SCOPE_AGENT) < phase) {
        __builtin_amdgcn_s_sleep(8);
      }
    }
  }
  __syncthreads();
}

// ---------------- persistent BiLSTM: block = (dir, 4-hidden-unit slice) x all 32 batches ----------------
// Weights LDS-resident (each value reused 32x/step). h exchanged via double-buffered global f64.
__global__ __launch_bounds__(256, 1) void k_lstm2(const float* __restrict__ xwt,   // [2][128][1600][32] f32
                                                  const float* __restrict__ whh_f, // [1600][400]
                                                  const float* __restrict__ whh_b,
                                                  const int* __restrict__ word_idxs,
                                                  double* __restrict__ hbuf,       // [2][2][400][32] f64
                                                  unsigned* __restrict__ bar,
                                                  float* __restrict__ enc) {
  __shared__ __align__(16) float  Wv[4 * 400 * 4];   // [u][k][g] 25.6 KB
  __shared__ __align__(16) double Sh[3200];          // union: hTile[100][32] | gpart[4][64][8]
  int bid = blockIdx.x;
  int d = bid / 100, slice = bid - d * 100;
  const float* whh = d ? whh_b : whh_f;
  const float* xwd = xwt + (size_t)d * SEQL * G4 * 32;
  int t = threadIdx.x;

  // one-time: stage Whh rows for our 4 units x 4 gates into LDS (interleaved [u][k][g])
  for (int p = 0; p < 16; ++p) {
    int u = p >> 2, g = p & 3;
    const float* src = whh + (size_t)(g * 400 + slice * 4 + u) * 400;
    for (int k = t; k < 400; k += 256) Wv[(u * 400 + k) * 4 + g] = src[k];
  }
  // init: zero our slice of parity-1 h buffer; c state in registers of threads t<128
  double cst = 0.0;
  int ub = t >> 5, bb = t & 31;     // updater mapping (t<128): unit ub (0..3), batch bb
  if (t < 128)
    hbuf[((size_t)1 * 2 + d) * 12800 + (size_t)(slice * 4 + ub) * 32 + bb] = 0.0;
  gridbar(bar, NBLK, 1);

  int slot = t & 63, kp = t >> 6;            // wave = kp (k-split of 4)
  int su = slot >> 4, sb2 = (slot & 15) * 2; // unit, batch-pair base

  for (int s = 0; s < SEQL; ++s) {
    int l = d ? (SEQL - 1 - s) : s;
    int rp = (s + 1) & 1, wp = s & 1;
    const double* hr = hbuf + ((size_t)rp * 2 + d) * 12800;
    double acc[8];
#pragma unroll
    for (int z = 0; z < 8; ++z) acc[z] = 0.0;

    for (int kt = 0; kt < 4; ++kt) {
      __syncthreads();   // previous tile / gpart consumption finished
      for (int i = t; i < 3200; i += 256) Sh[i] = hr[kt * 3200 + i];
      __syncthreads();
#pragma unroll
      for (int kk = 0; kk < 25; ++kk) {
        int klocal = kk * 4 + kp;
        double2 hp = *(const double2*)&Sh[klocal * 32 + sb2];
        float4 w4 = *(const float4*)&Wv[((size_t)su * 400 + kt * 100 + klocal) * 4];
        acc[0] = fma((double)w4.x, hp.x, acc[0]);
        acc[1] = fma((double)w4.x, hp.y, acc[1]);
        acc[2] = fma((double)w4.y, hp.x, acc[2]);
        acc[3] = fma((double)w4.y, hp.y, acc[3]);
        acc[4] = fma((double)w4.z, hp.x, acc[4]);
        acc[5] = fma((double)w4.z, hp.y, acc[5]);
        acc[6] = fma((double)w4.w, hp.x, acc[6]);
        acc[7] = fma((double)w4.w, hp.y, acc[7]);
      }
    }
    __syncthreads();
    // write partials: gpart[kp][slot][g*2+bbit]
    {
      double* gp = Sh + ((size_t)kp * 64 + slot) * 8;
#pragma unroll
      for (int z = 0; z < 8; ++z) gp[z] = acc[z];
    }
    __syncthreads();
    if (t < 128) {
      int slot2 = ub * 16 + (bb >> 1), bbit = bb & 1;
      int kglob = slice * 4 + ub;
      double g4v[4];
#pragma unroll
      for (int g = 0; g < 4; ++g) {
        double sum = Sh[((size_t)0 * 64 + slot2) * 8 + g * 2 + bbit]
                   + Sh[((size_t)1 * 64 + slot2) * 8 + g * 2 + bbit]
                   + Sh[((size_t)2 * 64 + slot2) * 8 + g * 2 + bbit]
                   + Sh[((size_t)3 * 64 + slot2) * 8 + g * 2 + bbit];
        sum += (double)xwd[((size_t)l * G4 + g * 400 + kglob) * 32 + bb];
        g4v[g] = sum;
      }
      bool m = word_idxs[bb * SEQL + l] > 0;
      double si = 1.0 / (1.0 + exp(-g4v[0]));
      double sf = 1.0 / (1.0 + exp(-g4v[1]));
      double so = 1.0 / (1.0 + exp(-g4v[3]));
      double cn = sf * cst + si * tanh(g4v[2]);
      double hn = so * tanh(cn);
      double hold = hr[(size_t)kglob * 32 + bb];
      double hw = m ? hn : hold;
      cst = m ? cn : cst;
      hbuf[((size_t)wp * 2 + d) * 12800 + (size_t)kglob * 32 + bb] = hw;
      enc[((size_t)bb * SEQL + l) * 800 + d * 400 + kglob] = m ? (float)hn : 0.f;
    }
    gridbar(bar, NBLK, s + 2);
  }
}

// ---------------- stage 2: score + argmax per (b,x), emits sort keys ----------------
__global__ __launch_bounds__(128) void k_stage2(const float* __restrict__ U,
                                                const float* __restrict__ y1T,
                                                const int* __restrict__ labels,
                                                unsigned long long* __restrict__ keys) {
  __shared__ double Ur[4644];
  int bx = blockIdx.x;          // b*128 + x
  int b = bx >> 7, x = bx & 127;
  const float* Urow = U + (size_t)bx * 4644;
  for (int i = threadIdx.x; i < 4644; i += 128) Ur[i] = (double)Urow[i];
  __syncthreads();
  int y = threadIdx.x;
  double acc[9];
#pragma unroll
  for (int o = 0; o < 9; ++o) acc[o] = 0.0;
  const float* yb = y1T + (size_t)b * 513 * 128 + y;
  for (int j = 0; j < 513; ++j) {
    double yv = (double)yb[(size_t)j * 128];
#pragma unroll
    for (int o = 0; o < 9; ++o) acc[o] = fma(Ur[o * 516 + j], yv, acc[o]);
  }
  double best = acc[0];
  int bi = 0;
#pragma unroll
  for (int o = 1; o < 9; ++o) {
    if (acc[o] > best) { best = acc[o]; bi = o; }
  }
  int fi = x * 128 + y;                      // per-sentence flat index
  int lab = labels[(size_t)bx * 128 + y];
  bool valid = (bi != 1) && (lab > 0);
  unsigned long long key;
  if (valid) {
    unsigned long long u = (unsigned long long)__double_as_longlong(best);
    unsigned long long mm = (u >> 63) ? ~u : (u | 0x8000000000000000ull); // ascending map
    unsigned long long dm = ~mm;                                          // descending
    key = (dm & ~0x3FFFFull) | ((unsigned long long)(unsigned)fi << 4) |
          (unsigned long long)(unsigned)bi;
  } else {
    key = ~0ull;
  }
  keys[(size_t)b * 16384 + fi] = key;
}

// ---------------- decode helpers ----------------
__device__ __forceinline__ void rangemask(int i, int j,
                                          unsigned long long& r0, unsigned long long& r1) {
  if (i > j) { r0 = 0ull; r1 = 0ull; return; }
  unsigned long long u0, u1;
  if (j >= 64) { u0 = ~0ull; u1 = (j >= 127) ? ~0ull : ((1ull << (j - 63)) - 1ull); }
  else         { u0 = (j == 63) ? ~0ull : ((1ull << (j + 1)) - 1ull); u1 = 0ull; }
  unsigned long long f0, f1;
  if (i >= 64) { f0 = 0ull; f1 = (~0ull) << (i - 64); }
  else         { f0 = (~0ull) << i; f1 = ~0ull; }
  r0 = u0 & f0; r1 = u1 & f1;
}

// ---------------- decode: sort + greedy NMS scan, one block per sentence ----------------
__global__ __launch_bounds__(1024) void k_decode(unsigned long long* __restrict__ keysg,
                                                 int* __restrict__ outp) {
  extern __shared__ unsigned long long lds[];     // 8192 keys = 64 KB
  int b = blockIdx.x;
  int t = threadIdx.x;
  unsigned long long* kg = keysg + (size_t)b * 16384;
  int* ob = outp + (size_t)b * 16384;

  for (int i = t; i < 16384; i += 1024) ob[i] = 1;
  __syncthreads();

  for (int hhalf = 0; hhalf < 2; ++hhalf) {
    for (int i = t; i < 8192; i += 1024) lds[i] = kg[hhalf * 8192 + i];
    __syncthreads();
    bool desc = (hhalf == 1);
    for (int k = 2; k <= 8192; k <<= 1) {
      for (int j = k >> 1; j > 0; j >>= 1) {
        for (int p = 0; p < 8; ++p) {
          int i = p * 1024 + t;
          int ix = i ^ j;
          if (ix > i) {
            unsigned long long ka = lds[i], kb = lds[ix];
            bool up = (((i & k) == 0) != desc);
            if (up ? (ka > kb) : (ka < kb)) { lds[i] = kb; lds[ix] = ka; }
          }
        }
        __syncthreads();
      }
    }
    for (int i = t; i < 8192; i += 1024) kg[hhalf * 8192 + i] = lds[i];
    __syncthreads();
  }
  for (int i = t; i < 8192; i += 1024) {
    unsigned long long ka = kg[i], kb = kg[i + 8192];
    if (ka > kb) { kg[i] = kb; kg[i + 8192] = ka; }
  }
  __syncthreads();
  for (int hhalf = 0; hhalf < 2; ++hhalf) {
    for (int i = t; i < 8192; i += 1024) lds[i] = kg[hhalf * 8192 + i];
    __syncthreads();
    for (int j = 4096; j > 0; j >>= 1) {
      for (int p = 0; p < 8; ++p) {
        int i = p * 1024 + t;
        int ix = i ^ j;
        if (ix > i) {
          unsigned long long ka = lds[i], kb = lds[ix];
          if (ka > kb) { lds[i] = kb; lds[ix] = ka; }
        }
      }
      __syncthreads();
    }
    for (int i = t; i < 8192; i += 1024) kg[hhalf * 8192 + i] = lds[i];
    __syncthreads();
  }

  if (t < 64) {
    const int lane = t;
    unsigned long long s0 = 0, s1 = 0, in0 = 0, in1 = 0;
    for (int base = 0; base < 16384; base += 64) {
      unsigned long long key = kg[base + lane];
      bool valid = (key != ~0ull);
      if (__ballot(valid) == 0ull) break;
      int fi = (int)((key >> 4) & 0x3FFFull);
      int ci = fi >> 7, cj = fi & 127, ca = (int)(key & 15ull);
      bool alive = valid;
      while (true) {
        bool conflict = false;
        {
          unsigned long long r0, r1;
          rangemask(ci, cj, r0, r1);
          if (((r0 & s0) | (r1 & s1)) != 0ull) conflict = true;
          unsigned long long ib = (ci < 64) ? (in0 >> ci) : (in1 >> (ci - 64));
          if (ib & 1ull) conflict = true;
        }
        unsigned long long elig = __ballot(alive && !conflict);
        if (elig == 0ull) break;
        int w = __ffsll((long long)elig) - 1;
        int wi = __shfl(ci, w), wj = __shfl(cj, w);
        if (lane == w) ob[fi] = ca;
        unsigned long long r0, r1;
        rangemask(wi, wj, r0, r1);
        in0 |= r0; in1 |= r1;
        if (wi < 64) s0 |= (1ull << wi); else s1 |= (1ull << (wi - 64));
        alive = alive && (lane > w);
      }
    }
  }
}

extern "C" void kernel_launch(void* const* d_in, const int* in_sizes, int n_in,
                              void* d_out, int out_size, void* d_ws, size_t ws_size,
                              hipStream_t stream) {
  const int*   word_idxs = (const int*)d_in[0];
  const int*   labels    = (const int*)d_in[1];
  const float* word_emb  = (const float*)d_in[2];
  const float* Wih_f = (const float*)d_in[3];
  const float* Whh_f = (const float*)d_in[4];
  const float* bih_f = (const float*)d_in[5];
  const float* bhh_f = (const float*)d_in[6];
  const float* Wih_b = (const float*)d_in[7];
  const float* Whh_b = (const float*)d_in[8];
  const float* bih_b = (const float*)d_in[9];
  const float* bhh_b = (const float*)d_in[10];
  const float* W_start = (const float*)d_in[11];
  const float* b_start = (const float*)d_in[12];
  const float* W_end   = (const float*)d_in[13];
  const float* b_end   = (const float*)d_in[14];
  const float* W_bi    = (const float*)d_in[15];

  char* ws = (char*)d_ws;
  float* x    = (float*)(ws + OFF_X);
  double* hbuf = (double*)(ws + OFF_HBUF);
  unsigned* bar = (unsigned*)(ws + OFF_BAR);
  float* XWt  = (float*)(ws + OFF_XW);
  float* enc  = (float*)(ws + OFF_ENC);
  float* U    = (float*)(ws + OFF_U);
  float* x1   = (float*)(ws + OFF_X1);
  float* y1T  = (float*)(ws + OFF_Y1T);
  float* Wbp  = (float*)(ws + OFF_WBP);
  unsigned long long* keys = (unsigned long long*)(ws + OFF_KEYS);
  int* outp = (int*)d_out;

  // 1. embedding gather
  k_gather<<<4096, 256, 0, stream>>>(word_idxs, word_emb, x);
  // 2. input-gate GEMMs, bias folded, stored transposed [d][l][gate][b]
  dim3 g2(64, 25);
  k_gemm_nt<<<g2, 256, 0, stream>>>(x, EMBD, Wih_f, EMBD, bih_f, bhh_f,
                                    XWt, 0, 4096, G4, EMBD, 2);
  k_gemm_nt<<<g2, 256, 0, stream>>>(x, EMBD, Wih_b, EMBD, bih_b, bhh_b,
                                    XWt + (size_t)SEQL * G4 * 32, 0, 4096, G4, EMBD, 2);
  // 3. barrier counters zero (x region now dead), then persistent LSTM
  hipMemsetAsync(ws + OFF_BAR, 0, 64, stream);
  k_lstm2<<<NBLK, 256, 0, stream>>>(XWt, Whh_f, Whh_b, word_idxs, hbuf, bar, enc);
  // 4. projections: x1 (hs, normal) and y1T (he, transposed)
  dim3 g4(64, 8);
  k_gemm_nt<<<g4, 256, 0, stream>>>(enc, 800, W_start, 800, b_start, nullptr,
                                    x1, 516, 4096, FF, 800, 0);
  k_gemm_nt<<<g4, 256, 0, stream>>>(enc, 800, W_end, 800, b_end, nullptr,
                                    y1T, 0, 4096, FF, 800, 1);
  k_ones<<<32, 256, 0, stream>>>(x1, y1T);
  // 5. biaffine stage 1: U[b,x][o][j] = sum_i x1[b,x,i] W[o,i,j]
  k_wbpad<<<(9 * 513 * 516 + 255) / 256, 256, 0, stream>>>(W_bi, Wbp);
  dim3 g5(64, 9, 9);
  k_gemm_nn<<<g5, 256, 0, stream>>>(x1, 516, Wbp, 516, (size_t)513 * 516,
                                    U, 4644, 4096, 513, 513);
  // 6. stage 2 + argmax + key build
  k_stage2<<<4096, 128, 0, stream>>>(U, y1T, labels, keys);
  // 7. sort + greedy NMS decode
  k_decode<<<32, 1024, 65536, stream>>>(keys, outp);
}

// Round 4
// 7391.433 us; speedup vs baseline: 1.1966x; 1.1966x over previous
//
#include <hip/hip_runtime.h>
#include <math.h>

// Problem constants
#define SEQL 128
#define NB   32
#define EMBD 300
#define HH   400      // hidden per direction
#define G4   1600     // 4*HH
#define FF   512
#define NLAB 9
#define NBLK 200      // persistent LSTM blocks: 2 dirs x 100 slices (4 hidden units each)
#define NGRP 8
#define GSZ  25       // NBLK / NGRP

// ---------------- workspace layout (bytes) ----------------
// x [4096][300] f32 at 0 (4,915,200) — dead after input GEMMs; hbuf/bar overlay it after.
static const size_t OFF_X    = 0;
static const size_t OFF_HBUF = 0;          // h double-buffer [2][2][400][32] f64 (819,200) — live only inside k_lstm2
static const size_t OFF_BAR  = 1048576;    // barrier counters (2 KB) — inside dead x region
static const size_t OFF_XW   = 5242880;    // XWt [2][128][1600][32] f32 (52,428,800) dead after LSTM
static const size_t OFF_ENC  = 62914560;   // enc [4096][800] f32 (13,107,200) dead after proj GEMMs
static const size_t OFF_U    = 0;          // U [4096][9][516] f32 (76,087,296) overlays everything above (post-LSTM)
static const size_t OFF_X1   = 76087296;   // x1 [4096][516] (513 used) (8,454,144)
static const size_t OFF_Y1T  = 84541440;   // y1T [32][513][128] (8,404,992)
static const size_t OFF_KEYS = 92946432;   // keys u64 [32][16384] (4,194,304)
static const size_t OFF_WBP  = 97140736;   // Wb padded [9][513][516] (9,529,488)

// ---------------- embedding gather ----------------
__global__ __launch_bounds__(256) void k_gather(const int* __restrict__ wi,
                                                const float* __restrict__ emb,
                                                float* __restrict__ x) {
  int m = blockIdx.x;                 // 0..4095 = b*128 + l
  int idx = wi[m];
  const float* src = emb + (size_t)idx * EMBD;
  float* dst = x + (size_t)m * EMBD;
  for (int e = threadIdx.x; e < EMBD; e += 256) dst[e] = src[e];
}

// ---------------- W_biaffine pad to stride 516 ----------------
__global__ __launch_bounds__(256) void k_wbpad(const float* __restrict__ wbi,
                                               float* __restrict__ wbp) {
  int tid = blockIdx.x * 256 + threadIdx.x;
  const int PER = 513 * 516;
  if (tid >= 9 * PER) return;
  int o = tid / PER;
  int r = tid - o * PER;
  int i = r / 516;
  int j = r - i * 516;
  wbp[tid] = (j < 513) ? wbi[(size_t)o * 513 * 513 + (size_t)i * 513 + j] : 0.f;
}

// ---------------- ones columns ----------------
__global__ __launch_bounds__(256) void k_ones(float* __restrict__ x1, float* __restrict__ y1T) {
  int tid = blockIdx.x * 256 + threadIdx.x;
  if (tid < 4096) {
    x1[(size_t)tid * 516 + 512] = 1.f;
  } else if (tid < 8192) {
    int r = tid - 4096;
    int bb = r >> 7, y = r & 127;
    y1T[((size_t)bb * 513 + 512) * 128 + y] = 1.f;
  }
}

// ---------------- tiled GEMM, f64 accumulate, C = A * W^T (+b1+b2)
// mode 0: normal store; mode 1: y1T transposed store; mode 2: XWt store [l][n][b]
__global__ __launch_bounds__(256) void k_gemm_nt(const float* __restrict__ A, int lda,
                                                 const float* __restrict__ W, int ldw,
                                                 const float* __restrict__ bias1,
                                                 const float* __restrict__ bias2,
                                                 float* __restrict__ C, int ldc,
                                                 int M, int N, int K, int mode) {
  __shared__ __align__(16) double As[16][68];
  __shared__ __align__(16) double Bs[16][68];
  int t = threadIdx.x;
  int m0 = blockIdx.x * 64, n0 = blockIdx.y * 64;
  int tm = t & 15, tn = t >> 4;
  int ar = t >> 2, akq = t & 3;
  double acc[4][4];
#pragma unroll
  for (int r = 0; r < 4; ++r)
#pragma unroll
    for (int c = 0; c < 4; ++c) acc[r][c] = 0.0;

  for (int k0 = 0; k0 < K; k0 += 16) {
    {
      const float* ap = A + (size_t)(m0 + ar) * lda + k0 + 4 * akq;
      float v0, v1, v2, v3;
      if (k0 + 4 * akq + 4 <= K) {
        float4 f = *(const float4*)ap; v0 = f.x; v1 = f.y; v2 = f.z; v3 = f.w;
      } else {
        v0 = (k0 + 4 * akq + 0 < K) ? ap[0] : 0.f;
        v1 = (k0 + 4 * akq + 1 < K) ? ap[1] : 0.f;
        v2 = (k0 + 4 * akq + 2 < K) ? ap[2] : 0.f;
        v3 = (k0 + 4 * akq + 3 < K) ? ap[3] : 0.f;
      }
      As[4 * akq + 0][ar] = (double)v0; As[4 * akq + 1][ar] = (double)v1;
      As[4 * akq + 2][ar] = (double)v2; As[4 * akq + 3][ar] = (double)v3;
    }
    {
      int nr = n0 + ar;
      float v0 = 0.f, v1 = 0.f, v2 = 0.f, v3 = 0.f;
      if (nr < N) {
        const float* wp = W + (size_t)nr * ldw + k0 + 4 * akq;
        if (k0 + 4 * akq + 4 <= K) {
          float4 f = *(const float4*)wp; v0 = f.x; v1 = f.y; v2 = f.z; v3 = f.w;
        } else {
          if (k0 + 4 * akq + 0 < K) v0 = wp[0];
          if (k0 + 4 * akq + 1 < K) v1 = wp[1];
          if (k0 + 4 * akq + 2 < K) v2 = wp[2];
          if (k0 + 4 * akq + 3 < K) v3 = wp[3];
        }
      }
      Bs[4 * akq + 0][ar] = (double)v0; Bs[4 * akq + 1][ar] = (double)v1;
      Bs[4 * akq + 2][ar] = (double)v2; Bs[4 * akq + 3][ar] = (double)v3;
    }
    __syncthreads();
#pragma unroll
    for (int kk = 0; kk < 16; ++kk) {
      double2 a01 = *(const double2*)&As[kk][4 * tm];
      double2 a23 = *(const double2*)&As[kk][4 * tm + 2];
      double2 b01 = *(const double2*)&Bs[kk][4 * tn];
      double2 b23 = *(const double2*)&Bs[kk][4 * tn + 2];
      double av[4] = {a01.x, a01.y, a23.x, a23.y};
      double bv[4] = {b01.x, b01.y, b23.x, b23.y};
#pragma unroll
      for (int r = 0; r < 4; ++r)
#pragma unroll
        for (int c = 0; c < 4; ++c) acc[r][c] = fma(av[r], bv[c], acc[r][c]);
    }
    __syncthreads();
  }
  double bn[4];
#pragma unroll
  for (int c = 0; c < 4; ++c) {
    int n = n0 + 4 * tn + c;
    double bv = 0.0;
    if (n < N) {
      if (bias1) bv += (double)bias1[n];
      if (bias2) bv += (double)bias2[n];
    }
    bn[c] = bv;
  }
  if (mode == 0) {
#pragma unroll
    for (int r = 0; r < 4; ++r) {
      int m = m0 + 4 * tm + r;
      float* cp = C + (size_t)m * ldc + n0 + 4 * tn;
      if (n0 + 4 * tn + 4 <= N) {
        float4 s = make_float4((float)(acc[r][0] + bn[0]), (float)(acc[r][1] + bn[1]),
                               (float)(acc[r][2] + bn[2]), (float)(acc[r][3] + bn[3]));
        *(float4*)cp = s;
      } else {
#pragma unroll
        for (int c = 0; c < 4; ++c)
          if (n0 + 4 * tn + c < N) cp[c] = (float)(acc[r][c] + bn[c]);
      }
    }
  } else if (mode == 1) {
    // transposed store into y1T[(b*513+n)*128 + y], m = b*128 + y
#pragma unroll
    for (int r = 0; r < 4; ++r) {
      int m = m0 + 4 * tm + r;
      int bb = m >> 7, y = m & 127;
#pragma unroll
      for (int c = 0; c < 4; ++c) {
        int n = n0 + 4 * tn + c;
        if (n < N) C[((size_t)bb * 513 + n) * 128 + y] = (float)(acc[r][c] + bn[c]);
      }
    }
  } else {
    // XWt store: C[(l*1600 + n)*32 + b], m = b*128 + l
#pragma unroll
    for (int r = 0; r < 4; ++r) {
      int m = m0 + 4 * tm + r;
      int bb = m >> 7, l = m & 127;
#pragma unroll
      for (int c = 0; c < 4; ++c) {
        int n = n0 + 4 * tn + c;
        if (n < N) C[((size_t)l * G4 + n) * 32 + bb] = (float)(acc[r][c] + bn[c]);
      }
    }
  }
}

// ---------------- tiled GEMM f64-acc, C(+o*516 col) = A * B (B row-major), batched over o ----------------
__global__ __launch_bounds__(256) void k_gemm_nn(const float* __restrict__ A, int lda,
                                                 const float* __restrict__ Bm, int ldb,
                                                 size_t strideB,
                                                 float* __restrict__ C, int ldc,
                                                 int M, int N, int K) {
  __shared__ __align__(16) double As[16][68];
  __shared__ __align__(16) double Bs[16][68];
  int t = threadIdx.x;
  int o = blockIdx.z;
  const float* B = Bm + (size_t)o * strideB;
  float* Cb = C + (size_t)o * 516;
  int m0 = blockIdx.x * 64, n0 = blockIdx.y * 64;
  int tm = t & 15, tn = t >> 4;
  int ar = t >> 2, akq = t & 3;
  double acc[4][4];
#pragma unroll
  for (int r = 0; r < 4; ++r)
#pragma unroll
    for (int c = 0; c < 4; ++c) acc[r][c] = 0.0;

  for (int k0 = 0; k0 < K; k0 += 16) {
    {
      const float* ap = A + (size_t)(m0 + ar) * lda + k0 + 4 * akq;
      float v0, v1, v2, v3;
      if (k0 + 4 * akq + 4 <= K) {
        float4 f = *(const float4*)ap; v0 = f.x; v1 = f.y; v2 = f.z; v3 = f.w;
      } else {
        v0 = (k0 + 4 * akq + 0 < K) ? ap[0] : 0.f;
        v1 = (k0 + 4 * akq + 1 < K) ? ap[1] : 0.f;
        v2 = (k0 + 4 * akq + 2 < K) ? ap[2] : 0.f;
        v3 = (k0 + 4 * akq + 3 < K) ? ap[3] : 0.f;
      }
      As[4 * akq + 0][ar] = (double)v0; As[4 * akq + 1][ar] = (double)v1;
      As[4 * akq + 2][ar] = (double)v2; As[4 * akq + 3][ar] = (double)v3;
    }
    {
      int kr = k0 + (t >> 4);
      int nc = n0 + 4 * (t & 15);
      float v0 = 0.f, v1 = 0.f, v2 = 0.f, v3 = 0.f;
      if (kr < K) {
        const float* bp = B + (size_t)kr * ldb + nc;
        if (nc + 4 <= N) {
          float4 f = *(const float4*)bp; v0 = f.x; v1 = f.y; v2 = f.z; v3 = f.w;
        } else {
          if (nc + 0 < N) v0 = bp[0];
          if (nc + 1 < N) v1 = bp[1];
          if (nc + 2 < N) v2 = bp[2];
          if (nc + 3 < N) v3 = bp[3];
        }
      }
      int kk = t >> 4, nq = 4 * (t & 15);
      Bs[kk][nq + 0] = (double)v0; Bs[kk][nq + 1] = (double)v1;
      Bs[kk][nq + 2] = (double)v2; Bs[kk][nq + 3] = (double)v3;
    }
    __syncthreads();
#pragma unroll
    for (int kk = 0; kk < 16; ++kk) {
      double2 a01 = *(const double2*)&As[kk][4 * tm];
      double2 a23 = *(const double2*)&As[kk][4 * tm + 2];
      double2 b01 = *(const double2*)&Bs[kk][4 * tn];
      double2 b23 = *(const double2*)&Bs[kk][4 * tn + 2];
      double av[4] = {a01.x, a01.y, a23.x, a23.y};
      double bv[4] = {b01.x, b01.y, b23.x, b23.y};
#pragma unroll
      for (int r = 0; r < 4; ++r)
#pragma unroll
        for (int c = 0; c < 4; ++c) acc[r][c] = fma(av[r], bv[c], acc[r][c]);
    }
    __syncthreads();
  }
#pragma unroll
  for (int r = 0; r < 4; ++r) {
    int m = m0 + 4 * tm + r;
    float* cp = Cb + (size_t)m * ldc + n0 + 4 * tn;
    if (n0 + 4 * tn + 4 <= N) {
      *(float4*)cp = make_float4((float)acc[r][0], (float)acc[r][1],
                                 (float)acc[r][2], (float)acc[r][3]);
    } else {
#pragma unroll
      for (int c = 0; c < 4; ++c)
        if (n0 + 4 * tn + c < N) cp[c] = (float)acc[r][c];
    }
  }
}

// ---------------- two-level grid barrier (200 blocks co-resident) ----------------
// bar layout (u32, 128B-separated lines): group g counter @ bar[32*g] (g<8),
// root @ bar[32*8], epoch @ bar[32*9].
// Design: RELAXED arrival RMWs (no per-op L2 wb/inv), one __threadfence release
// per block (after __syncthreads has drained all waves' vmcnt), RELAXED spin
// (no L2 invalidate per poll), single ACQUIRE load on exit (one buffer_inv).
__device__ __forceinline__ void gridbar2(unsigned* bar, unsigned phase) {
  __syncthreads();   // drains vmcnt of all waves: every thread's global stores complete
  if (threadIdx.x == 0) {
    __threadfence();  // push this block's dirty L2 lines (h slice, enc) to IF
    unsigned g = (unsigned)blockIdx.x / GSZ;
    unsigned a = __hip_atomic_fetch_add(&bar[32u * g], 1u, __ATOMIC_RELAXED,
                                        __HIP_MEMORY_SCOPE_AGENT);
    if (a == GSZ - 1) {
      __hip_atomic_store(&bar[32u * g], 0u, __ATOMIC_RELAXED, __HIP_MEMORY_SCOPE_AGENT);
      unsigned r = __hip_atomic_fetch_add(&bar[32u * 8], 1u, __ATOMIC_RELAXED,
                                          __HIP_MEMORY_SCOPE_AGENT);
      if (r == NGRP - 1) {
        __hip_atomic_store(&bar[32u * 8], 0u, __ATOMIC_RELAXED, __HIP_MEMORY_SCOPE_AGENT);
        __hip_atomic_store(&bar[32u * 9], phase, __ATOMIC_RELEASE, __HIP_MEMORY_SCOPE_AGENT);
      }
    }
    while (__hip_atomic_load(&bar[32u * 9], __ATOMIC_RELAXED,
                             __HIP_MEMORY_SCOPE_AGENT) < phase) {
      __builtin_amdgcn_s_sleep(2);
    }
    (void)__hip_atomic_load(&bar[32u * 9], __ATOMIC_ACQUIRE,
                            __HIP_MEMORY_SCOPE_AGENT);  // single L2 invalidate
  }
  __syncthreads();
}

// ---------------- persistent BiLSTM: block = (dir, 4-hidden-unit slice) x all 32 batches ----------------
// Weights LDS-resident (each value reused 32x/step). h exchanged via double-buffered global f64.
__global__ __launch_bounds__(256, 1) void k_lstm2(const float* __restrict__ xwt,   // [2][128][1600][32] f32
                                                  const float* __restrict__ whh_f, // [1600][400]
                                                  const float* __restrict__ whh_b,
                                                  const int* __restrict__ word_idxs,
                                                  double* __restrict__ hbuf,       // [2][2][400][32] f64
                                                  unsigned* __restrict__ bar,
                                                  float* __restrict__ enc) {
  __shared__ __align__(16) float  Wv[4 * 400 * 4];   // [u][k][g] 25.6 KB
  __shared__ __align__(16) double Sh[3200];          // union: hTile[100][32] | gpart[4][64][8]
  int bid = blockIdx.x;
  int d = bid / 100, slice = bid - d * 100;
  const float* whh = d ? whh_b : whh_f;
  const float* xwd = xwt + (size_t)d * SEQL * G4 * 32;
  int t = threadIdx.x;

  // one-time: stage Whh rows for our 4 units x 4 gates into LDS (interleaved [u][k][g])
  for (int p = 0; p < 16; ++p) {
    int u = p >> 2, g = p & 3;
    const float* src = whh + (size_t)(g * 400 + slice * 4 + u) * 400;
    for (int k = t; k < 400; k += 256) Wv[(u * 400 + k) * 4 + g] = src[k];
  }
  // init: zero our slice of parity-1 h buffer; c state in registers of threads t<128
  double cst = 0.0;
  int ub = t >> 5, bb = t & 31;     // updater mapping (t<128): unit ub (0..3), batch bb
  if (t < 128)
    hbuf[((size_t)1 * 2 + d) * 12800 + (size_t)(slice * 4 + ub) * 32 + bb] = 0.0;
  gridbar2(bar, 1);

  int slot = t & 63, kp = t >> 6;            // wave = kp (k-split of 4)
  int su = slot >> 4, sb2 = (slot & 15) * 2; // unit, batch-pair base

  for (int s = 0; s < SEQL; ++s) {
    int l = d ? (SEQL - 1 - s) : s;
    int rp = (s + 1) & 1, wp = s & 1;
    const double* hr = hbuf + ((size_t)rp * 2 + d) * 12800;
    double acc[8];
#pragma unroll
    for (int z = 0; z < 8; ++z) acc[z] = 0.0;

    for (int kt = 0; kt < 4; ++kt) {
      __syncthreads();   // previous tile / gpart consumption finished
      for (int i = t; i < 3200; i += 256) Sh[i] = hr[kt * 3200 + i];
      __syncthreads();
#pragma unroll
      for (int kk = 0; kk < 25; ++kk) {
        int klocal = kk * 4 + kp;
        double2 hp = *(const double2*)&Sh[klocal * 32 + sb2];
        float4 w4 = *(const float4*)&Wv[((size_t)su * 400 + kt * 100 + klocal) * 4];
        acc[0] = fma((double)w4.x, hp.x, acc[0]);
        acc[1] = fma((double)w4.x, hp.y, acc[1]);
        acc[2] = fma((double)w4.y, hp.x, acc[2]);
        acc[3] = fma((double)w4.y, hp.y, acc[3]);
        acc[4] = fma((double)w4.z, hp.x, acc[4]);
        acc[5] = fma((double)w4.z, hp.y, acc[5]);
        acc[6] = fma((double)w4.w, hp.x, acc[6]);
        acc[7] = fma((double)w4.w, hp.y, acc[7]);
      }
    }
    __syncthreads();
    // write partials: gpart[kp][slot][g*2+bbit]
    {
      double* gp = Sh + ((size_t)kp * 64 + slot) * 8;
#pragma unroll
      for (int z = 0; z < 8; ++z) gp[z] = acc[z];
    }
    __syncthreads();
    if (t < 128) {
      int slot2 = ub * 16 + (bb >> 1), bbit = bb & 1;
      int kglob = slice * 4 + ub;
      double g4v[4];
#pragma unroll
      for (int g = 0; g < 4; ++g) {
        double sum = Sh[((size_t)0 * 64 + slot2) * 8 + g * 2 + bbit]
                   + Sh[((size_t)1 * 64 + slot2) * 8 + g * 2 + bbit]
                   + Sh[((size_t)2 * 64 + slot2) * 8 + g * 2 + bbit]
                   + Sh[((size_t)3 * 64 + slot2) * 8 + g * 2 + bbit];
        sum += (double)xwd[((size_t)l * G4 + g * 400 + kglob) * 32 + bb];
        g4v[g] = sum;
      }
      bool m = word_idxs[bb * SEQL + l] > 0;
      double si = 1.0 / (1.0 + exp(-g4v[0]));
      double sf = 1.0 / (1.0 + exp(-g4v[1]));
      double so = 1.0 / (1.0 + exp(-g4v[3]));
      double cn = sf * cst + si * tanh(g4v[2]);
      double hn = so * tanh(cn);
      double hold = hr[(size_t)kglob * 32 + bb];
      double hw = m ? hn : hold;
      cst = m ? cn : cst;
      hbuf[((size_t)wp * 2 + d) * 12800 + (size_t)kglob * 32 + bb] = hw;
      enc[((size_t)bb * SEQL + l) * 800 + d * 400 + kglob] = m ? (float)hn : 0.f;
    }
    gridbar2(bar, s + 2);
  }
}

// ---------------- stage 2: score + argmax per (b,x), emits sort keys ----------------
__global__ __launch_bounds__(128) void k_stage2(const float* __restrict__ U,
                                                const float* __restrict__ y1T,
                                                const int* __restrict__ labels,
                                                unsigned long long* __restrict__ keys) {
  __shared__ double Ur[4644];
  int bx = blockIdx.x;          // b*128 + x
  int b = bx >> 7, x = bx & 127;
  const float* Urow = U + (size_t)bx * 4644;
  for (int i = threadIdx.x; i < 4644; i += 128) Ur[i] = (double)Urow[i];
  __syncthreads();
  int y = threadIdx.x;
  double acc[9];
#pragma unroll
  for (int o = 0; o < 9; ++o) acc[o] = 0.0;
  const float* yb = y1T + (size_t)b * 513 * 128 + y;
  for (int j = 0; j < 513; ++j) {
    double yv = (double)yb[(size_t)j * 128];
#pragma unroll
    for (int o = 0; o < 9; ++o) acc[o] = fma(Ur[o * 516 + j], yv, acc[o]);
  }
  double best = acc[0];
  int bi = 0;
#pragma unroll
  for (int o = 1; o < 9; ++o) {
    if (acc[o] > best) { best = acc[o]; bi = o; }
  }
  int fi = x * 128 + y;                      // per-sentence flat index
  int lab = labels[(size_t)bx * 128 + y];
  bool valid = (bi != 1) && (lab > 0);
  unsigned long long key;
  if (valid) {
    unsigned long long u = (unsigned long long)__double_as_longlong(best);
    unsigned long long mm = (u >> 63) ? ~u : (u | 0x8000000000000000ull); // ascending map
    unsigned long long dm = ~mm;                                          // descending
    key = (dm & ~0x3FFFFull) | ((unsigned long long)(unsigned)fi << 4) |
          (unsigned long long)(unsigned)bi;
  } else {
    key = ~0ull;
  }
  keys[(size_t)b * 16384 + fi] = key;
}

// ---------------- decode helpers ----------------
__device__ __forceinline__ void rangemask(int i, int j,
                                          unsigned long long& r0, unsigned long long& r1) {
  if (i > j) { r0 = 0ull; r1 = 0ull; return; }
  unsigned long long u0, u1;
  if (j >= 64) { u0 = ~0ull; u1 = (j >= 127) ? ~0ull : ((1ull << (j - 63)) - 1ull); }
  else         { u0 = (j == 63) ? ~0ull : ((1ull << (j + 1)) - 1ull); u1 = 0ull; }
  unsigned long long f0, f1;
  if (i >= 64) { f0 = 0ull; f1 = (~0ull) << (i - 64); }
  else         { f0 = (~0ull) << i; f1 = ~0ull; }
  r0 = u0 & f0; r1 = u1 & f1;
}

// ---------------- decode: sort + greedy NMS scan, one block per sentence ----------------
__global__ __launch_bounds__(1024) void k_decode(unsigned long long* __restrict__ keysg,
                                                 int* __restrict__ outp) {
  extern __shared__ unsigned long long lds[];     // 8192 keys = 64 KB
  int b = blockIdx.x;
  int t = threadIdx.x;
  unsigned long long* kg = keysg + (size_t)b * 16384;
  int* ob = outp + (size_t)b * 16384;

  for (int i = t; i < 16384; i += 1024) ob[i] = 1;
  __syncthreads();

  for (int hhalf = 0; hhalf < 2; ++hhalf) {
    for (int i = t; i < 8192; i += 1024) lds[i] = kg[hhalf * 8192 + i];
    __syncthreads();
    bool desc = (hhalf == 1);
    for (int k = 2; k <= 8192; k <<= 1) {
      for (int j = k >> 1; j > 0; j >>= 1) {
        for (int p = 0; p < 8; ++p) {
          int i = p * 1024 + t;
          int ix = i ^ j;
          if (ix > i) {
            unsigned long long ka = lds[i], kb = lds[ix];
            bool up = (((i & k) == 0) != desc);
            if (up ? (ka > kb) : (ka < kb)) { lds[i] = kb; lds[ix] = ka; }
          }
        }
        __syncthreads();
      }
    }
    for (int i = t; i < 8192; i += 1024) kg[hhalf * 8192 + i] = lds[i];
    __syncthreads();
  }
  for (int i = t; i < 8192; i += 1024) {
    unsigned long long ka = kg[i], kb = kg[i + 8192];
    if (ka > kb) { kg[i] = kb; kg[i + 8192] = ka; }
  }
  __syncthreads();
  for (int hhalf = 0; hhalf < 2; ++hhalf) {
    for (int i = t; i < 8192; i += 1024) lds[i] = kg[hhalf * 8192 + i];
    __syncthreads();
    for (int j = 4096; j > 0; j >>= 1) {
      for (int p = 0; p < 8; ++p) {
        int i = p * 1024 + t;
        int ix = i ^ j;
        if (ix > i) {
          unsigned long long ka = lds[i], kb = lds[ix];
          if (ka > kb) { lds[i] = kb; lds[ix] = ka; }
        }
      }
      __syncthreads();
    }
    for (int i = t; i < 8192; i += 1024) kg[hhalf * 8192 + i] = lds[i];
    __syncthreads();
  }

  if (t < 64) {
    const int lane = t;
    unsigned long long s0 = 0, s1 = 0, in0 = 0, in1 = 0;
    for (int base = 0; base < 16384; base += 64) {
      unsigned long long key = kg[base + lane];
      bool valid = (key != ~0ull);
      if (__ballot(valid) == 0ull) break;
      int fi = (int)((key >> 4) & 0x3FFFull);
      int ci = fi >> 7, cj = fi & 127, ca = (int)(key & 15ull);
      bool alive = valid;
      while (true) {
        bool conflict = false;
        {
          unsigned long long r0, r1;
          rangemask(ci, cj, r0, r1);
          if (((r0 & s0) | (r1 & s1)) != 0ull) conflict = true;
          unsigned long long ib = (ci < 64) ? (in0 >> ci) : (in1 >> (ci - 64));
          if (ib & 1ull) conflict = true;
        }
        unsigned long long elig = __ballot(alive && !conflict);
        if (elig == 0ull) break;
        int w = __ffsll((long long)elig) - 1;
        int wi = __shfl(ci, w), wj = __shfl(cj, w);
        if (lane == w) ob[fi] = ca;
        unsigned long long r0, r1;
        rangemask(wi, wj, r0, r1);
        in0 |= r0; in1 |= r1;
        if (wi < 64) s0 |= (1ull << wi); else s1 |= (1ull << (wi - 64));
        alive = alive && (lane > w);
      }
    }
  }
}

extern "C" void kernel_launch(void* const* d_in, const int* in_sizes, int n_in,
                              void* d_out, int out_size, void* d_ws, size_t ws_size,
                              hipStream_t stream) {
  const int*   word_idxs = (const int*)d_in[0];
  const int*   labels    = (const int*)d_in[1];
  const float* word_emb  = (const float*)d_in[2];
  const float* Wih_f = (const float*)d_in[3];
  const float* Whh_f = (const float*)d_in[4];
  const float* bih_f = (const float*)d_in[5];
  const float* bhh_f = (const float*)d_in[6];
  const float* Wih_b = (const float*)d_in[7];
  const float* Whh_b = (const float*)d_in[8];
  const float* bih_b = (const float*)d_in[9];
  const float* bhh_b = (const float*)d_in[10];
  const float* W_start = (const float*)d_in[11];
  const float* b_start = (const float*)d_in[12];
  const float* W_end   = (const float*)d_in[13];
  const float* b_end   = (const float*)d_in[14];
  const float* W_bi    = (const float*)d_in[15];

  char* ws = (char*)d_ws;
  float* x    = (float*)(ws + OFF_X);
  double* hbuf = (double*)(ws + OFF_HBUF);
  unsigned* bar = (unsigned*)(ws + OFF_BAR);
  float* XWt  = (float*)(ws + OFF_XW);
  float* enc  = (float*)(ws + OFF_ENC);
  float* U    = (float*)(ws + OFF_U);
  float* x1   = (float*)(ws + OFF_X1);
  float* y1T  = (float*)(ws + OFF_Y1T);
  float* Wbp  = (float*)(ws + OFF_WBP);
  unsigned long long* keys = (unsigned long long*)(ws + OFF_KEYS);
  int* outp = (int*)d_out;

  // 1. embedding gather
  k_gather<<<4096, 256, 0, stream>>>(word_idxs, word_emb, x);
  // 2. input-gate GEMMs, bias folded, stored transposed [d][l][gate][b]
  dim3 g2(64, 25);
  k_gemm_nt<<<g2, 256, 0, stream>>>(x, EMBD, Wih_f, EMBD, bih_f, bhh_f,
                                    XWt, 0, 4096, G4, EMBD, 2);
  k_gemm_nt<<<g2, 256, 0, stream>>>(x, EMBD, Wih_b, EMBD, bih_b, bhh_b,
                                    XWt + (size_t)SEQL * G4 * 32, 0, 4096, G4, EMBD, 2);
  // 3. barrier counters zero (x region now dead), then persistent LSTM
  hipMemsetAsync(ws + OFF_BAR, 0, 2048, stream);
  k_lstm2<<<NBLK, 256, 0, stream>>>(XWt, Whh_f, Whh_b, word_idxs, hbuf, bar, enc);
  // 4. projections: x1 (hs, normal) and y1T (he, transposed)
  dim3 g4(64, 8);
  k_gemm_nt<<<g4, 256, 0, stream>>>(enc, 800, W_start, 800, b_start, nullptr,
                                    x1, 516, 4096, FF, 800, 0);
  k_gemm_nt<<<g4, 256, 0, stream>>>(enc, 800, W_end, 800, b_end, nullptr,
                                    y1T, 0, 4096, FF, 800, 1);
  k_ones<<<32, 256, 0, stream>>>(x1, y1T);
  // 5. biaffine stage 1: U[b,x][o][j] = sum_i x1[b,x,i] W[o,i,j]
  k_wbpad<<<(9 * 513 * 516 + 255) / 256, 256, 0, stream>>>(W_bi, Wbp);
  dim3 g5(64, 9, 9);
  k_gemm_nn<<<g5, 256, 0, stream>>>(x1, 516, Wbp, 516, (size_t)513 * 516,
                                    U, 4644, 4096, 513, 513);
  // 6. stage 2 + argmax + key build
  k_stage2<<<4096, 128, 0, stream>>>(U, y1T, labels, keys);
  // 7. sort + greedy NMS decode
  k_decode<<<32, 1024, 65536, stream>>>(keys, outp);
}

// Round 5
// 6288.827 us; speedup vs baseline: 1.4064x; 1.1753x over previous
//
#include <hip/hip_runtime.h>
#include <math.h>

// Problem constants
#define SEQL 128
#define NB   32
#define EMBD 300
#define HH   400      // hidden per direction
#define G4   1600     // 4*HH
#define FF   512
#define NLAB 9
#define NBLK 200      // persistent LSTM blocks: 2 dirs x 100 slices (4 hidden units each)
#define NGRP2 4       // barrier groups per direction
#define GSZ2  25      // blocks per group (100 / 4)

// ---------------- workspace layout (bytes) ----------------
// x [4096][300] f32 at 0 (4,915,200) — dead after input GEMMs; hbuf/bar overlay it after.
static const size_t OFF_X    = 0;
static const size_t OFF_HBUF = 0;          // h double-buffer [2][2][400][32] f64 (819,200) — live only inside k_lstm2
static const size_t OFF_BAR  = 1048576;    // barrier counters (2 dirs x 1 KB) — inside dead x region
static const size_t OFF_XW   = 5242880;    // XWt [2][128][1600][32] f32 (52,428,800) dead after LSTM
static const size_t OFF_ENC  = 62914560;   // enc [4096][800] f32 (13,107,200) dead after proj GEMMs
static const size_t OFF_U    = 0;          // U [4096][9][516] f32 (76,087,296) overlays everything above (post-LSTM)
static const size_t OFF_X1   = 76087296;   // x1 [4096][516] (513 used) (8,454,144)
static const size_t OFF_Y1T  = 84541440;   // y1T [32][513][128] (8,404,992)
static const size_t OFF_KEYS = 92946432;   // keys u64 [32][16384] (4,194,304)
static const size_t OFF_WBP  = 97140736;   // Wb padded [9][513][516] (9,529,488)

// ---------------- agent-scope (IF-coherent, cache-bypassing) accessors ----------------
__device__ __forceinline__ double aload(const double* p) {
  return __hip_atomic_load((const double*)p, __ATOMIC_RELAXED, __HIP_MEMORY_SCOPE_AGENT);
}
__device__ __forceinline__ void astore(double* p, double v) {
  __hip_atomic_store(p, v, __ATOMIC_RELAXED, __HIP_MEMORY_SCOPE_AGENT);
}

// ---------------- embedding gather ----------------
__global__ __launch_bounds__(256) void k_gather(const int* __restrict__ wi,
                                                const float* __restrict__ emb,
                                                float* __restrict__ x) {
  int m = blockIdx.x;                 // 0..4095 = b*128 + l
  int idx = wi[m];
  const float* src = emb + (size_t)idx * EMBD;
  float* dst = x + (size_t)m * EMBD;
  for (int e = threadIdx.x; e < EMBD; e += 256) dst[e] = src[e];
}

// ---------------- W_biaffine pad to stride 516 ----------------
__global__ __launch_bounds__(256) void k_wbpad(const float* __restrict__ wbi,
                                               float* __restrict__ wbp) {
  int tid = blockIdx.x * 256 + threadIdx.x;
  const int PER = 513 * 516;
  if (tid >= 9 * PER) return;
  int o = tid / PER;
  int r = tid - o * PER;
  int i = r / 516;
  int j = r - i * 516;
  wbp[tid] = (j < 513) ? wbi[(size_t)o * 513 * 513 + (size_t)i * 513 + j] : 0.f;
}

// ---------------- ones columns ----------------
__global__ __launch_bounds__(256) void k_ones(float* __restrict__ x1, float* __restrict__ y1T) {
  int tid = blockIdx.x * 256 + threadIdx.x;
  if (tid < 4096) {
    x1[(size_t)tid * 516 + 512] = 1.f;
  } else if (tid < 8192) {
    int r = tid - 4096;
    int bb = r >> 7, y = r & 127;
    y1T[((size_t)bb * 513 + 512) * 128 + y] = 1.f;
  }
}

// ---------------- tiled GEMM, f64 accumulate, C = A * W^T (+b1+b2)
// mode 0: normal store; mode 1: y1T transposed store; mode 2: XWt store [l][n][b]
__global__ __launch_bounds__(256) void k_gemm_nt(const float* __restrict__ A, int lda,
                                                 const float* __restrict__ W, int ldw,
                                                 const float* __restrict__ bias1,
                                                 const float* __restrict__ bias2,
                                                 float* __restrict__ C, int ldc,
                                                 int M, int N, int K, int mode) {
  __shared__ __align__(16) double As[16][68];
  __shared__ __align__(16) double Bs[16][68];
  int t = threadIdx.x;
  int m0 = blockIdx.x * 64, n0 = blockIdx.y * 64;
  int tm = t & 15, tn = t >> 4;
  int ar = t >> 2, akq = t & 3;
  double acc[4][4];
#pragma unroll
  for (int r = 0; r < 4; ++r)
#pragma unroll
    for (int c = 0; c < 4; ++c) acc[r][c] = 0.0;

  for (int k0 = 0; k0 < K; k0 += 16) {
    {
      const float* ap = A + (size_t)(m0 + ar) * lda + k0 + 4 * akq;
      float v0, v1, v2, v3;
      if (k0 + 4 * akq + 4 <= K) {
        float4 f = *(const float4*)ap; v0 = f.x; v1 = f.y; v2 = f.z; v3 = f.w;
      } else {
        v0 = (k0 + 4 * akq + 0 < K) ? ap[0] : 0.f;
        v1 = (k0 + 4 * akq + 1 < K) ? ap[1] : 0.f;
        v2 = (k0 + 4 * akq + 2 < K) ? ap[2] : 0.f;
        v3 = (k0 + 4 * akq + 3 < K) ? ap[3] : 0.f;
      }
      As[4 * akq + 0][ar] = (double)v0; As[4 * akq + 1][ar] = (double)v1;
      As[4 * akq + 2][ar] = (double)v2; As[4 * akq + 3][ar] = (double)v3;
    }
    {
      int nr = n0 + ar;
      float v0 = 0.f, v1 = 0.f, v2 = 0.f, v3 = 0.f;
      if (nr < N) {
        const float* wp = W + (size_t)nr * ldw + k0 + 4 * akq;
        if (k0 + 4 * akq + 4 <= K) {
          float4 f = *(const float4*)wp; v0 = f.x; v1 = f.y; v2 = f.z; v3 = f.w;
        } else {
          if (k0 + 4 * akq + 0 < K) v0 = wp[0];
          if (k0 + 4 * akq + 1 < K) v1 = wp[1];
          if (k0 + 4 * akq + 2 < K) v2 = wp[2];
          if (k0 + 4 * akq + 3 < K) v3 = wp[3];
        }
      }
      Bs[4 * akq + 0][ar] = (double)v0; Bs[4 * akq + 1][ar] = (double)v1;
      Bs[4 * akq + 2][ar] = (double)v2; Bs[4 * akq + 3][ar] = (double)v3;
    }
    __syncthreads();
#pragma unroll
    for (int kk = 0; kk < 16; ++kk) {
      double2 a01 = *(const double2*)&As[kk][4 * tm];
      double2 a23 = *(const double2*)&As[kk][4 * tm + 2];
      double2 b01 = *(const double2*)&Bs[kk][4 * tn];
      double2 b23 = *(const double2*)&Bs[kk][4 * tn + 2];
      double av[4] = {a01.x, a01.y, a23.x, a23.y};
      double bv[4] = {b01.x, b01.y, b23.x, b23.y};
#pragma unroll
      for (int r = 0; r < 4; ++r)
#pragma unroll
        for (int c = 0; c < 4; ++c) acc[r][c] = fma(av[r], bv[c], acc[r][c]);
    }
    __syncthreads();
  }
  double bn[4];
#pragma unroll
  for (int c = 0; c < 4; ++c) {
    int n = n0 + 4 * tn + c;
    double bv = 0.0;
    if (n < N) {
      if (bias1) bv += (double)bias1[n];
      if (bias2) bv += (double)bias2[n];
    }
    bn[c] = bv;
  }
  if (mode == 0) {
#pragma unroll
    for (int r = 0; r < 4; ++r) {
      int m = m0 + 4 * tm + r;
      float* cp = C + (size_t)m * ldc + n0 + 4 * tn;
      if (n0 + 4 * tn + 4 <= N) {
        float4 s = make_float4((float)(acc[r][0] + bn[0]), (float)(acc[r][1] + bn[1]),
                               (float)(acc[r][2] + bn[2]), (float)(acc[r][3] + bn[3]));
        *(float4*)cp = s;
      } else {
#pragma unroll
        for (int c = 0; c < 4; ++c)
          if (n0 + 4 * tn + c < N) cp[c] = (float)(acc[r][c] + bn[c]);
      }
    }
  } else if (mode == 1) {
    // transposed store into y1T[(b*513+n)*128 + y], m = b*128 + y
#pragma unroll
    for (int r = 0; r < 4; ++r) {
      int m = m0 + 4 * tm + r;
      int bb = m >> 7, y = m & 127;
#pragma unroll
      for (int c = 0; c < 4; ++c) {
        int n = n0 + 4 * tn + c;
        if (n < N) C[((size_t)bb * 513 + n) * 128 + y] = (float)(acc[r][c] + bn[c]);
      }
    }
  } else {
    // XWt store: C[(l*1600 + n)*32 + b], m = b*128 + l
#pragma unroll
    for (int r = 0; r < 4; ++r) {
      int m = m0 + 4 * tm + r;
      int bb = m >> 7, l = m & 127;
#pragma unroll
      for (int c = 0; c < 4; ++c) {
        int n = n0 + 4 * tn + c;
        if (n < N) C[((size_t)l * G4 + n) * 32 + bb] = (float)(acc[r][c] + bn[c]);
      }
    }
  }
}

// ---------------- tiled GEMM f64-acc, C(+o*516 col) = A * B (B row-major), batched over o ----------------
__global__ __launch_bounds__(256) void k_gemm_nn(const float* __restrict__ A, int lda,
                                                 const float* __restrict__ Bm, int ldb,
                                                 size_t strideB,
                                                 float* __restrict__ C, int ldc,
                                                 int M, int N, int K) {
  __shared__ __align__(16) double As[16][68];
  __shared__ __align__(16) double Bs[16][68];
  int t = threadIdx.x;
  int o = blockIdx.z;
  const float* B = Bm + (size_t)o * strideB;
  float* Cb = C + (size_t)o * 516;
  int m0 = blockIdx.x * 64, n0 = blockIdx.y * 64;
  int tm = t & 15, tn = t >> 4;
  int ar = t >> 2, akq = t & 3;
  double acc[4][4];
#pragma unroll
  for (int r = 0; r < 4; ++r)
#pragma unroll
    for (int c = 0; c < 4; ++c) acc[r][c] = 0.0;

  for (int k0 = 0; k0 < K; k0 += 16) {
    {
      const float* ap = A + (size_t)(m0 + ar) * lda + k0 + 4 * akq;
      float v0, v1, v2, v3;
      if (k0 + 4 * akq + 4 <= K) {
        float4 f = *(const float4*)ap; v0 = f.x; v1 = f.y; v2 = f.z; v3 = f.w;
      } else {
        v0 = (k0 + 4 * akq + 0 < K) ? ap[0] : 0.f;
        v1 = (k0 + 4 * akq + 1 < K) ? ap[1] : 0.f;
        v2 = (k0 + 4 * akq + 2 < K) ? ap[2] : 0.f;
        v3 = (k0 + 4 * akq + 3 < K) ? ap[3] : 0.f;
      }
      As[4 * akq + 0][ar] = (double)v0; As[4 * akq + 1][ar] = (double)v1;
      As[4 * akq + 2][ar] = (double)v2; As[4 * akq + 3][ar] = (double)v3;
    }
    {
      int kr = k0 + (t >> 4);
      int nc = n0 + 4 * (t & 15);
      float v0 = 0.f, v1 = 0.f, v2 = 0.f, v3 = 0.f;
      if (kr < K) {
        const float* bp = B + (size_t)kr * ldb + nc;
        if (nc + 4 <= N) {
          float4 f = *(const float4*)bp; v0 = f.x; v1 = f.y; v2 = f.z; v3 = f.w;
        } else {
          if (nc + 0 < N) v0 = bp[0];
          if (nc + 1 < N) v1 = bp[1];
          if (nc + 2 < N) v2 = bp[2];
          if (nc + 3 < N) v3 = bp[3];
        }
      }
      int kk = t >> 4, nq = 4 * (t & 15);
      Bs[kk][nq + 0] = (double)v0; Bs[kk][nq + 1] = (double)v1;
      Bs[kk][nq + 2] = (double)v2; Bs[kk][nq + 3] = (double)v3;
    }
    __syncthreads();
#pragma unroll
    for (int kk = 0; kk < 16; ++kk) {
      double2 a01 = *(const double2*)&As[kk][4 * tm];
      double2 a23 = *(const double2*)&As[kk][4 * tm + 2];
      double2 b01 = *(const double2*)&Bs[kk][4 * tn];
      double2 b23 = *(const double2*)&Bs[kk][4 * tn + 2];
      double av[4] = {a01.x, a01.y, a23.x, a23.y};
      double bv[4] = {b01.x, b01.y, b23.x, b23.y};
#pragma unroll
      for (int r = 0; r < 4; ++r)
#pragma unroll
        for (int c = 0; c < 4; ++c) acc[r][c] = fma(av[r], bv[c], acc[r][c]);
    }
    __syncthreads();
  }
#pragma unroll
  for (int r = 0; r < 4; ++r) {
    int m = m0 + 4 * tm + r;
    float* cp = Cb + (size_t)m * ldc + n0 + 4 * tn;
    if (n0 + 4 * tn + 4 <= N) {
      *(float4*)cp = make_float4((float)acc[r][0], (float)acc[r][1],
                                 (float)acc[r][2], (float)acc[r][3]);
    } else {
#pragma unroll
      for (int c = 0; c < 4; ++c)
        if (n0 + 4 * tn + c < N) cp[c] = (float)acc[r][c];
    }
  }
}

// ---------------- per-direction grid barrier, zero cache-maintenance ----------------
// bar layout per dir (u32, 128B lines): group g @ bar[32*g] (g<4), root @ bar[32*4],
// epoch @ bar[32*5]. Monotonic counters (no resets → no ABA): arrival leader is the
// fetch_add that returns phase*GSZ2-1. All data crossing the barrier travels via
// agent-scope sc1 load/stores (IF-resident), so no threadfence / wbl2 / buffer_inv
// is needed anywhere. __syncthreads before arrival guarantees every wave's sc1
// stores retired (globally visible) before the leader's RMW reaches IF.
__device__ __forceinline__ void gridbar3(unsigned* bar, unsigned phase, int slice) {
  __syncthreads();
  if (threadIdx.x == 0) {
    unsigned g = (unsigned)slice / GSZ2;
    unsigned a = __hip_atomic_fetch_add(&bar[32u * g], 1u, __ATOMIC_RELAXED,
                                        __HIP_MEMORY_SCOPE_AGENT);
    if (a == phase * GSZ2 - 1u) {
      unsigned r = __hip_atomic_fetch_add(&bar[32u * 4], 1u, __ATOMIC_RELAXED,
                                          __HIP_MEMORY_SCOPE_AGENT);
      if (r == phase * NGRP2 - 1u) {
        __hip_atomic_store(&bar[32u * 5], phase, __ATOMIC_RELAXED,
                           __HIP_MEMORY_SCOPE_AGENT);
      }
    }
    while (__hip_atomic_load(&bar[32u * 5], __ATOMIC_RELAXED,
                             __HIP_MEMORY_SCOPE_AGENT) < phase) {
      __builtin_amdgcn_s_sleep(4);
    }
    // compiler-ordering only (workgroup scope: no L2 invalidate emitted)
    (void)__hip_atomic_load(&bar[32u * 5], __ATOMIC_ACQUIRE,
                            __HIP_MEMORY_SCOPE_WORKGROUP);
  }
  __syncthreads();
}

// ---------------- persistent BiLSTM: block = (dir, 4-hidden-unit slice) x all 32 batches ----------------
// Weights LDS-resident (each value reused 32x/step). h exchanged via double-buffered
// global f64 using agent-scope (IF-coherent) accesses; per-direction barriers.
__global__ __launch_bounds__(256, 1) void k_lstm2(const float* __restrict__ xwt,   // [2][128][1600][32] f32
                                                  const float* __restrict__ whh_f, // [1600][400]
                                                  const float* __restrict__ whh_b,
                                                  const int* __restrict__ word_idxs,
                                                  double* __restrict__ hbuf,       // [2][2][400][32] f64
                                                  unsigned* __restrict__ bar,      // [2][256] u32
                                                  float* __restrict__ enc) {
  __shared__ __align__(16) float  Wv[4 * 400 * 4];   // [u][k][g] 25.6 KB
  __shared__ __align__(16) double Sh[3200];          // union: hTile[100][32] | gpart[4][64][8]
  int bid = blockIdx.x;
  int d = bid / 100, slice = bid - d * 100;
  const float* whh = d ? whh_b : whh_f;
  const float* xwd = xwt + (size_t)d * SEQL * G4 * 32;
  unsigned* bard = bar + (size_t)d * 256;
  int t = threadIdx.x;

  // one-time: stage Whh rows for our 4 units x 4 gates into LDS (interleaved [u][k][g])
  for (int p = 0; p < 16; ++p) {
    int u = p >> 2, g = p & 3;
    const float* src = whh + (size_t)(g * 400 + slice * 4 + u) * 400;
    for (int k = t; k < 400; k += 256) Wv[(u * 400 + k) * 4 + g] = src[k];
  }
  // init: zero our slice of parity-1 h buffer; c state in registers of threads t<128
  double cst = 0.0;
  int ub = t >> 5, bb = t & 31;     // updater mapping (t<128): unit ub (0..3), batch bb
  if (t < 128)
    astore(&hbuf[((size_t)1 * 2 + d) * 12800 + (size_t)(slice * 4 + ub) * 32 + bb], 0.0);
  gridbar3(bard, 1, slice);

  int slot = t & 63, kp = t >> 6;            // wave = kp (k-split of 4)
  int su = slot >> 4, sb2 = (slot & 15) * 2; // unit, batch-pair base

  for (int s = 0; s < SEQL; ++s) {
    int l = d ? (SEQL - 1 - s) : s;
    int rp = (s + 1) & 1, wp = s & 1;
    const double* hr = hbuf + ((size_t)rp * 2 + d) * 12800;
    double acc[8];
#pragma unroll
    for (int z = 0; z < 8; ++z) acc[z] = 0.0;

    for (int kt = 0; kt < 4; ++kt) {
      __syncthreads();   // previous tile / gpart consumption finished
      for (int i = t; i < 3200; i += 256) Sh[i] = aload(&hr[kt * 3200 + i]);
      __syncthreads();
#pragma unroll
      for (int kk = 0; kk < 25; ++kk) {
        int klocal = kk * 4 + kp;
        double2 hp = *(const double2*)&Sh[klocal * 32 + sb2];
        float4 w4 = *(const float4*)&Wv[((size_t)su * 400 + kt * 100 + klocal) * 4];
        acc[0] = fma((double)w4.x, hp.x, acc[0]);
        acc[1] = fma((double)w4.x, hp.y, acc[1]);
        acc[2] = fma((double)w4.y, hp.x, acc[2]);
        acc[3] = fma((double)w4.y, hp.y, acc[3]);
        acc[4] = fma((double)w4.z, hp.x, acc[4]);
        acc[5] = fma((double)w4.z, hp.y, acc[5]);
        acc[6] = fma((double)w4.w, hp.x, acc[6]);
        acc[7] = fma((double)w4.w, hp.y, acc[7]);
      }
    }
    __syncthreads();
    // write partials: gpart[kp][slot][g*2+bbit]
    {
      double* gp = Sh + ((size_t)kp * 64 + slot) * 8;
#pragma unroll
      for (int z = 0; z < 8; ++z) gp[z] = acc[z];
    }
    __syncthreads();
    if (t < 128) {
      int slot2 = ub * 16 + (bb >> 1), bbit = bb & 1;
      int kglob = slice * 4 + ub;
      double g4v[4];
#pragma unroll
      for (int g = 0; g < 4; ++g) {
        double sum = Sh[((size_t)0 * 64 + slot2) * 8 + g * 2 + bbit]
                   + Sh[((size_t)1 * 64 + slot2) * 8 + g * 2 + bbit]
                   + Sh[((size_t)2 * 64 + slot2) * 8 + g * 2 + bbit]
                   + Sh[((size_t)3 * 64 + slot2) * 8 + g * 2 + bbit];
        sum += (double)xwd[((size_t)l * G4 + g * 400 + kglob) * 32 + bb];
        g4v[g] = sum;
      }
      bool m = word_idxs[bb * SEQL + l] > 0;
      double si = 1.0 / (1.0 + exp(-g4v[0]));
      double sf = 1.0 / (1.0 + exp(-g4v[1]));
      double so = 1.0 / (1.0 + exp(-g4v[3]));
      double cn = sf * cst + si * tanh(g4v[2]);
      double hn = so * tanh(cn);
      double hold = aload(&hr[(size_t)kglob * 32 + bb]);
      double hw = m ? hn : hold;
      cst = m ? cn : cst;
      astore(&hbuf[((size_t)wp * 2 + d) * 12800 + (size_t)kglob * 32 + bb], hw);
      enc[((size_t)bb * SEQL + l) * 800 + d * 400 + kglob] = m ? (float)hn : 0.f;
    }
    gridbar3(bard, s + 2, slice);
  }
}

// ---------------- stage 2: score + argmax per (b,x), emits sort keys ----------------
__global__ __launch_bounds__(128) void k_stage2(const float* __restrict__ U,
                                                const float* __restrict__ y1T,
                                                const int* __restrict__ labels,
                                                unsigned long long* __restrict__ keys) {
  __shared__ double Ur[4644];
  int bx = blockIdx.x;          // b*128 + x
  int b = bx >> 7, x = bx & 127;
  const float* Urow = U + (size_t)bx * 4644;
  for (int i = threadIdx.x; i < 4644; i += 128) Ur[i] = (double)Urow[i];
  __syncthreads();
  int y = threadIdx.x;
  double acc[9];
#pragma unroll
  for (int o = 0; o < 9; ++o) acc[o] = 0.0;
  const float* yb = y1T + (size_t)b * 513 * 128 + y;
  for (int j = 0; j < 513; ++j) {
    double yv = (double)yb[(size_t)j * 128];
#pragma unroll
    for (int o = 0; o < 9; ++o) acc[o] = fma(Ur[o * 516 + j], yv, acc[o]);
  }
  double best = acc[0];
  int bi = 0;
#pragma unroll
  for (int o = 1; o < 9; ++o) {
    if (acc[o] > best) { best = acc[o]; bi = o; }
  }
  int fi = x * 128 + y;                      // per-sentence flat index
  int lab = labels[(size_t)bx * 128 + y];
  bool valid = (bi != 1) && (lab > 0);
  unsigned long long key;
  if (valid) {
    unsigned long long u = (unsigned long long)__double_as_longlong(best);
    unsigned long long mm = (u >> 63) ? ~u : (u | 0x8000000000000000ull); // ascending map
    unsigned long long dm = ~mm;                                          // descending
    key = (dm & ~0x3FFFFull) | ((unsigned long long)(unsigned)fi << 4) |
          (unsigned long long)(unsigned)bi;
  } else {
    key = ~0ull;
  }
  keys[(size_t)b * 16384 + fi] = key;
}

// ---------------- decode helpers ----------------
__device__ __forceinline__ void rangemask(int i, int j,
                                          unsigned long long& r0, unsigned long long& r1) {
  if (i > j) { r0 = 0ull; r1 = 0ull; return; }
  unsigned long long u0, u1;
  if (j >= 64) { u0 = ~0ull; u1 = (j >= 127) ? ~0ull : ((1ull << (j - 63)) - 1ull); }
  else         { u0 = (j == 63) ? ~0ull : ((1ull << (j + 1)) - 1ull); u1 = 0ull; }
  unsigned long long f0, f1;
  if (i >= 64) { f0 = 0ull; f1 = (~0ull) << (i - 64); }
  else         { f0 = (~0ull) << i; f1 = ~0ull; }
  r0 = u0 & f0; r1 = u1 & f1;
}

// ---------------- decode: sort + greedy NMS scan, one block per sentence ----------------
__global__ __launch_bounds__(1024) void k_decode(unsigned long long* __restrict__ keysg,
                                                 int* __restrict__ outp) {
  extern __shared__ unsigned long long lds[];     // 8192 keys = 64 KB
  int b = blockIdx.x;
  int t = threadIdx.x;
  unsigned long long* kg = keysg + (size_t)b * 16384;
  int* ob = outp + (size_t)b * 16384;

  for (int i = t; i < 16384; i += 1024) ob[i] = 1;
  __syncthreads();

  for (int hhalf = 0; hhalf < 2; ++hhalf) {
    for (int i = t; i < 8192; i += 1024) lds[i] = kg[hhalf * 8192 + i];
    __syncthreads();
    bool desc = (hhalf == 1);
    for (int k = 2; k <= 8192; k <<= 1) {
      for (int j = k >> 1; j > 0; j >>= 1) {
        for (int p = 0; p < 8; ++p) {
          int i = p * 1024 + t;
          int ix = i ^ j;
          if (ix > i) {
            unsigned long long ka = lds[i], kb = lds[ix];
            bool up = (((i & k) == 0) != desc);
            if (up ? (ka > kb) : (ka < kb)) { lds[i] = kb; lds[ix] = ka; }
          }
        }
        __syncthreads();
      }
    }
    for (int i = t; i < 8192; i += 1024) kg[hhalf * 8192 + i] = lds[i];
    __syncthreads();
  }
  for (int i = t; i < 8192; i += 1024) {
    unsigned long long ka = kg[i], kb = kg[i + 8192];
    if (ka > kb) { kg[i] = kb; kg[i + 8192] = ka; }
  }
  __syncthreads();
  for (int hhalf = 0; hhalf < 2; ++hhalf) {
    for (int i = t; i < 8192; i += 1024) lds[i] = kg[hhalf * 8192 + i];
    __syncthreads();
    for (int j = 4096; j > 0; j >>= 1) {
      for (int p = 0; p < 8; ++p) {
        int i = p * 1024 + t;
        int ix = i ^ j;
        if (ix > i) {
          unsigned long long ka = lds[i], kb = lds[ix];
          if (ka > kb) { lds[i] = kb; lds[ix] = ka; }
        }
      }
      __syncthreads();
    }
    for (int i = t; i < 8192; i += 1024) kg[hhalf * 8192 + i] = lds[i];
    __syncthreads();
  }

  if (t < 64) {
    const int lane = t;
    unsigned long long s0 = 0, s1 = 0, in0 = 0, in1 = 0;
    for (int base = 0; base < 16384; base += 64) {
      unsigned long long key = kg[base + lane];
      bool valid = (key != ~0ull);
      if (__ballot(valid) == 0ull) break;
      int fi = (int)((key >> 4) & 0x3FFFull);
      int ci = fi >> 7, cj = fi & 127, ca = (int)(key & 15ull);
      bool alive = valid;
      while (true) {
        bool conflict = false;
        {
          unsigned long long r0, r1;
          rangemask(ci, cj, r0, r1);
          if (((r0 & s0) | (r1 & s1)) != 0ull) conflict = true;
          unsigned long long ib = (ci < 64) ? (in0 >> ci) : (in1 >> (ci - 64));
          if (ib & 1ull) conflict = true;
        }
        unsigned long long elig = __ballot(alive && !conflict);
        if (elig == 0ull) break;
        int w = __ffsll((long long)elig) - 1;
        int wi = __shfl(ci, w), wj = __shfl(cj, w);
        if (lane == w) ob[fi] = ca;
        unsigned long long r0, r1;
        rangemask(wi, wj, r0, r1);
        in0 |= r0; in1 |= r1;
        if (wi < 64) s0 |= (1ull << wi); else s1 |= (1ull << (wi - 64));
        alive = alive && (lane > w);
      }
    }
  }
}

extern "C" void kernel_launch(void* const* d_in, const int* in_sizes, int n_in,
                              void* d_out, int out_size, void* d_ws, size_t ws_size,
                              hipStream_t stream) {
  const int*   word_idxs = (const int*)d_in[0];
  const int*   labels    = (const int*)d_in[1];
  const float* word_emb  = (const float*)d_in[2];
  const float* Wih_f = (const float*)d_in[3];
  const float* Whh_f = (const float*)d_in[4];
  const float* bih_f = (const float*)d_in[5];
  const float* bhh_f = (const float*)d_in[6];
  const float* Wih_b = (const float*)d_in[7];
  const float* Whh_b = (const float*)d_in[8];
  const float* bih_b = (const float*)d_in[9];
  const float* bhh_b = (const float*)d_in[10];
  const float* W_start = (const float*)d_in[11];
  const float* b_start = (const float*)d_in[12];
  const float* W_end   = (const float*)d_in[13];
  const float* b_end   = (const float*)d_in[14];
  const float* W_bi    = (const float*)d_in[15];

  char* ws = (char*)d_ws;
  float* x    = (float*)(ws + OFF_X);
  double* hbuf = (double*)(ws + OFF_HBUF);
  unsigned* bar = (unsigned*)(ws + OFF_BAR);
  float* XWt  = (float*)(ws + OFF_XW);
  float* enc  = (float*)(ws + OFF_ENC);
  float* U    = (float*)(ws + OFF_U);
  float* x1   = (float*)(ws + OFF_X1);
  float* y1T  = (float*)(ws + OFF_Y1T);
  float* Wbp  = (float*)(ws + OFF_WBP);
  unsigned long long* keys = (unsigned long long*)(ws + OFF_KEYS);
  int* outp = (int*)d_out;

  // 1. embedding gather
  k_gather<<<4096, 256, 0, stream>>>(word_idxs, word_emb, x);
  // 2. input-gate GEMMs, bias folded, stored transposed [d][l][gate][b]
  dim3 g2(64, 25);
  k_gemm_nt<<<g2, 256, 0, stream>>>(x, EMBD, Wih_f, EMBD, bih_f, bhh_f,
                                    XWt, 0, 4096, G4, EMBD, 2);
  k_gemm_nt<<<g2, 256, 0, stream>>>(x, EMBD, Wih_b, EMBD, bih_b, bhh_b,
                                    XWt + (size_t)SEQL * G4 * 32, 0, 4096, G4, EMBD, 2);
  // 3. barrier counters zero (x region now dead), then persistent LSTM
  hipMemsetAsync(ws + OFF_BAR, 0, 4096, stream);
  k_lstm2<<<NBLK, 256, 0, stream>>>(XWt, Whh_f, Whh_b, word_idxs, hbuf, bar, enc);
  // 4. projections: x1 (hs, normal) and y1T (he, transposed)
  dim3 g4(64, 8);
  k_gemm_nt<<<g4, 256, 0, stream>>>(enc, 800, W_start, 800, b_start, nullptr,
                                    x1, 516, 4096, FF, 800, 0);
  k_gemm_nt<<<g4, 256, 0, stream>>>(enc, 800, W_end, 800, b_end, nullptr,
                                    y1T, 0, 4096, FF, 800, 1);
  k_ones<<<32, 256, 0, stream>>>(x1, y1T);
  // 5. biaffine stage 1: U[b,x][o][j] = sum_i x1[b,x,i] W[o,i,j]
  k_wbpad<<<(9 * 513 * 516 + 255) / 256, 256, 0, stream>>>(W_bi, Wbp);
  dim3 g5(64, 9, 9);
  k_gemm_nn<<<g5, 256, 0, stream>>>(x1, 516, Wbp, 516, (size_t)513 * 516,
                                    U, 4644, 4096, 513, 513);
  // 6. stage 2 + argmax + key build
  k_stage2<<<4096, 128, 0, stream>>>(U, y1T, labels, keys);
  // 7. sort + greedy NMS decode
  k_decode<<<32, 1024, 65536, stream>>>(keys, outp);
}

// Round 6
// 6212.219 us; speedup vs baseline: 1.4237x; 1.0123x over previous
//
#include <hip/hip_runtime.h>
#include <math.h>

// Problem constants
#define SEQL 128
#define NB   32
#define EMBD 300
#define HH   400      // hidden per direction
#define G4   1600     // 4*HH
#define FF   512
#define NLAB 9
#define NBLK 200      // persistent LSTM blocks: 2 dirs x 100 slices (4 hidden units each)

// ---------------- workspace layout (bytes) ----------------
static const size_t OFF_X    = 0;          // x [4096][300] f32 — dead after input GEMMs
static const size_t OFF_HBUF = 0;          // h double-buffer [2][2][400][32] f64 (819,200) — live only in k_lstm3
static const size_t OFF_FLG  = 1048576;    // publish flags [2][128] u32 — in dead x region
static const size_t OFF_XW   = 5242880;    // XWt [2][128][32][1600] f32 (52,428,800) dead after LSTM; he reuses it
static const size_t OFF_HE   = 5242880;    // he [4096][512] f32 (8,388,608) — after LSTM, before gemm_nn
static const size_t OFF_ENC  = 62914560;   // enc [4096][800] f32 (13,107,200) dead after proj GEMMs
static const size_t OFF_U    = 0;          // U [4096][9][516] f32 (76,087,296) overlays all of the above post-proj
static const size_t OFF_X1   = 76087296;   // x1 [4096][516] (8,454,144)
static const size_t OFF_Y1T  = 84541440;   // y1T [32][513][128] (8,404,992)
static const size_t OFF_KEYS = 92946432;   // keys u64 [32][16384] (4,194,304)
static const size_t OFF_WBP  = 97140736;   // Wb padded [9][513][516] (9,529,488)

// ---------------- agent-scope (IF-coherent, cache-bypassing) accessors ----------------
__device__ __forceinline__ double aload(const double* p) {
  return __hip_atomic_load(p, __ATOMIC_RELAXED, __HIP_MEMORY_SCOPE_AGENT);
}
__device__ __forceinline__ void astore(double* p, double v) {
  __hip_atomic_store(p, v, __ATOMIC_RELAXED, __HIP_MEMORY_SCOPE_AGENT);
}
__device__ __forceinline__ unsigned afload(const unsigned* p) {
  return __hip_atomic_load(p, __ATOMIC_RELAXED, __HIP_MEMORY_SCOPE_AGENT);
}
__device__ __forceinline__ void afstore(unsigned* p, unsigned v) {
  __hip_atomic_store(p, v, __ATOMIC_RELAXED, __HIP_MEMORY_SCOPE_AGENT);
}

// ---------------- embedding gather ----------------
__global__ __launch_bounds__(256) void k_gather(const int* __restrict__ wi,
                                                const float* __restrict__ emb,
                                                float* __restrict__ x) {
  int m = blockIdx.x;
  int idx = wi[m];
  const float* src = emb + (size_t)idx * EMBD;
  float* dst = x + (size_t)m * EMBD;
  for (int e = threadIdx.x; e < EMBD; e += 256) dst[e] = src[e];
}

// ---------------- W_biaffine pad to stride 516 ----------------
__global__ __launch_bounds__(256) void k_wbpad(const float* __restrict__ wbi,
                                               float* __restrict__ wbp) {
  int tid = blockIdx.x * 256 + threadIdx.x;
  const int PER = 513 * 516;
  if (tid >= 9 * PER) return;
  int o = tid / PER;
  int r = tid - o * PER;
  int i = r / 516;
  int j = r - i * 516;
  wbp[tid] = (j < 513) ? wbi[(size_t)o * 513 * 513 + (size_t)i * 513 + j] : 0.f;
}

// ---------------- ones columns ----------------
__global__ __launch_bounds__(256) void k_ones(float* __restrict__ x1, float* __restrict__ y1T) {
  int tid = blockIdx.x * 256 + threadIdx.x;
  if (tid < 4096) {
    x1[(size_t)tid * 516 + 512] = 1.f;
  } else if (tid < 8192) {
    int r = tid - 4096;
    int bb = r >> 7, y = r & 127;
    y1T[((size_t)bb * 513 + 512) * 128 + y] = 1.f;
  }
}

// ---------------- he -> y1T transpose (coalesced both sides) ----------------
__global__ __launch_bounds__(256) void k_y1t(const float* __restrict__ he,
                                             float* __restrict__ y1T) {
  __shared__ float tile[32][33];
  int b = blockIdx.z;
  int n0 = blockIdx.x * 32, y0 = blockIdx.y * 32;
  int tx = threadIdx.x & 31, ty = threadIdx.x >> 5;
  for (int yy = ty; yy < 32; yy += 8)
    tile[yy][tx] = he[((size_t)b * 128 + y0 + yy) * 512 + n0 + tx];
  __syncthreads();
  for (int nn = ty; nn < 32; nn += 8)
    y1T[((size_t)b * 513 + n0 + nn) * 128 + y0 + tx] = tile[tx][nn];
}

// ---------------- tiled GEMM, f64 accumulate, C = A * W^T (+b1+b2)
// mode 0: normal store (ldc); mode 2: XWt store [l][b][n] (coalesced)
__global__ __launch_bounds__(256) void k_gemm_nt(const float* __restrict__ A, int lda,
                                                 const float* __restrict__ W, int ldw,
                                                 const float* __restrict__ bias1,
                                                 const float* __restrict__ bias2,
                                                 float* __restrict__ C, int ldc,
                                                 int M, int N, int K, int mode) {
  __shared__ __align__(16) double As[16][68];
  __shared__ __align__(16) double Bs[16][68];
  int t = threadIdx.x;
  int m0 = blockIdx.x * 64, n0 = blockIdx.y * 64;
  int tm = t & 15, tn = t >> 4;
  int ar = t >> 2, akq = t & 3;
  double acc[4][4];
#pragma unroll
  for (int r = 0; r < 4; ++r)
#pragma unroll
    for (int c = 0; c < 4; ++c) acc[r][c] = 0.0;

  for (int k0 = 0; k0 < K; k0 += 16) {
    {
      const float* ap = A + (size_t)(m0 + ar) * lda + k0 + 4 * akq;
      float v0, v1, v2, v3;
      if (k0 + 4 * akq + 4 <= K) {
        float4 f = *(const float4*)ap; v0 = f.x; v1 = f.y; v2 = f.z; v3 = f.w;
      } else {
        v0 = (k0 + 4 * akq + 0 < K) ? ap[0] : 0.f;
        v1 = (k0 + 4 * akq + 1 < K) ? ap[1] : 0.f;
        v2 = (k0 + 4 * akq + 2 < K) ? ap[2] : 0.f;
        v3 = (k0 + 4 * akq + 3 < K) ? ap[3] : 0.f;
      }
      As[4 * akq + 0][ar] = (double)v0; As[4 * akq + 1][ar] = (double)v1;
      As[4 * akq + 2][ar] = (double)v2; As[4 * akq + 3][ar] = (double)v3;
    }
    {
      int nr = n0 + ar;
      float v0 = 0.f, v1 = 0.f, v2 = 0.f, v3 = 0.f;
      if (nr < N) {
        const float* wp = W + (size_t)nr * ldw + k0 + 4 * akq;
        if (k0 + 4 * akq + 4 <= K) {
          float4 f = *(const float4*)wp; v0 = f.x; v1 = f.y; v2 = f.z; v3 = f.w;
        } else {
          if (k0 + 4 * akq + 0 < K) v0 = wp[0];
          if (k0 + 4 * akq + 1 < K) v1 = wp[1];
          if (k0 + 4 * akq + 2 < K) v2 = wp[2];
          if (k0 + 4 * akq + 3 < K) v3 = wp[3];
        }
      }
      Bs[4 * akq + 0][ar] = (double)v0; Bs[4 * akq + 1][ar] = (double)v1;
      Bs[4 * akq + 2][ar] = (double)v2; Bs[4 * akq + 3][ar] = (double)v3;
    }
    __syncthreads();
#pragma unroll
    for (int kk = 0; kk < 16; ++kk) {
      double2 a01 = *(const double2*)&As[kk][4 * tm];
      double2 a23 = *(const double2*)&As[kk][4 * tm + 2];
      double2 b01 = *(const double2*)&Bs[kk][4 * tn];
      double2 b23 = *(const double2*)&Bs[kk][4 * tn + 2];
      double av[4] = {a01.x, a01.y, a23.x, a23.y};
      double bv[4] = {b01.x, b01.y, b23.x, b23.y};
#pragma unroll
      for (int r = 0; r < 4; ++r)
#pragma unroll
        for (int c = 0; c < 4; ++c) acc[r][c] = fma(av[r], bv[c], acc[r][c]);
    }
    __syncthreads();
  }
  double bn[4];
#pragma unroll
  for (int c = 0; c < 4; ++c) {
    int n = n0 + 4 * tn + c;
    double bv = 0.0;
    if (n < N) {
      if (bias1) bv += (double)bias1[n];
      if (bias2) bv += (double)bias2[n];
    }
    bn[c] = bv;
  }
  if (mode == 0) {
#pragma unroll
    for (int r = 0; r < 4; ++r) {
      int m = m0 + 4 * tm + r;
      float* cp = C + (size_t)m * ldc + n0 + 4 * tn;
      if (n0 + 4 * tn + 4 <= N) {
        float4 s = make_float4((float)(acc[r][0] + bn[0]), (float)(acc[r][1] + bn[1]),
                               (float)(acc[r][2] + bn[2]), (float)(acc[r][3] + bn[3]));
        *(float4*)cp = s;
      } else {
#pragma unroll
        for (int c = 0; c < 4; ++c)
          if (n0 + 4 * tn + c < N) cp[c] = (float)(acc[r][c] + bn[c]);
      }
    }
  } else {
    // XWt store: row = l*32 + b (m = b*128 + l), coalesced float4 in n
#pragma unroll
    for (int r = 0; r < 4; ++r) {
      int m = m0 + 4 * tm + r;
      int bb = m >> 7, l = m & 127;
      float* cp = C + ((size_t)l * 32 + bb) * G4 + n0 + 4 * tn;
      float4 s = make_float4((float)(acc[r][0] + bn[0]), (float)(acc[r][1] + bn[1]),
                             (float)(acc[r][2] + bn[2]), (float)(acc[r][3] + bn[3]));
      *(float4*)cp = s;
    }
  }
}

// ---------------- tiled GEMM f64-acc, C(+o*516 col) = A * B (B row-major), batched over o ----------------
__global__ __launch_bounds__(256) void k_gemm_nn(const float* __restrict__ A, int lda,
                                                 const float* __restrict__ Bm, int ldb,
                                                 size_t strideB,
                                                 float* __restrict__ C, int ldc,
                                                 int M, int N, int K) {
  __shared__ __align__(16) double As[16][68];
  __shared__ __align__(16) double Bs[16][68];
  int t = threadIdx.x;
  int o = blockIdx.z;
  const float* B = Bm + (size_t)o * strideB;
  float* Cb = C + (size_t)o * 516;
  int m0 = blockIdx.x * 64, n0 = blockIdx.y * 64;
  int tm = t & 15, tn = t >> 4;
  int ar = t >> 2, akq = t & 3;
  double acc[4][4];
#pragma unroll
  for (int r = 0; r < 4; ++r)
#pragma unroll
    for (int c = 0; c < 4; ++c) acc[r][c] = 0.0;

  for (int k0 = 0; k0 < K; k0 += 16) {
    {
      const float* ap = A + (size_t)(m0 + ar) * lda + k0 + 4 * akq;
      float v0, v1, v2, v3;
      if (k0 + 4 * akq + 4 <= K) {
        float4 f = *(const float4*)ap; v0 = f.x; v1 = f.y; v2 = f.z; v3 = f.w;
      } else {
        v0 = (k0 + 4 * akq + 0 < K) ? ap[0] : 0.f;
        v1 = (k0 + 4 * akq + 1 < K) ? ap[1] : 0.f;
        v2 = (k0 + 4 * akq + 2 < K) ? ap[2] : 0.f;
        v3 = (k0 + 4 * akq + 3 < K) ? ap[3] : 0.f;
      }
      As[4 * akq + 0][ar] = (double)v0; As[4 * akq + 1][ar] = (double)v1;
      As[4 * akq + 2][ar] = (double)v2; As[4 * akq + 3][ar] = (double)v3;
    }
    {
      int kr = k0 + (t >> 4);
      int nc = n0 + 4 * (t & 15);
      float v0 = 0.f, v1 = 0.f, v2 = 0.f, v3 = 0.f;
      if (kr < K) {
        const float* bp = B + (size_t)kr * ldb + nc;
        if (nc + 4 <= N) {
          float4 f = *(const float4*)bp; v0 = f.x; v1 = f.y; v2 = f.z; v3 = f.w;
        } else {
          if (nc + 0 < N) v0 = bp[0];
          if (nc + 1 < N) v1 = bp[1];
          if (nc + 2 < N) v2 = bp[2];
          if (nc + 3 < N) v3 = bp[3];
        }
      }
      int kk = t >> 4, nq = 4 * (t & 15);
      Bs[kk][nq + 0] = (double)v0; Bs[kk][nq + 1] = (double)v1;
      Bs[kk][nq + 2] = (double)v2; Bs[kk][nq + 3] = (double)v3;
    }
    __syncthreads();
#pragma unroll
    for (int kk = 0; kk < 16; ++kk) {
      double2 a01 = *(const double2*)&As[kk][4 * tm];
      double2 a23 = *(const double2*)&As[kk][4 * tm + 2];
      double2 b01 = *(const double2*)&Bs[kk][4 * tn];
      double2 b23 = *(const double2*)&Bs[kk][4 * tn + 2];
      double av[4] = {a01.x, a01.y, a23.x, a23.y};
      double bv[4] = {b01.x, b01.y, b23.x, b23.y};
#pragma unroll
      for (int r = 0; r < 4; ++r)
#pragma unroll
        for (int c = 0; c < 4; ++c) acc[r][c] = fma(av[r], bv[c], acc[r][c]);
    }
    __syncthreads();
  }
#pragma unroll
  for (int r = 0; r < 4; ++r) {
    int m = m0 + 4 * tm + r;
    float* cp = Cb + (size_t)m * ldc + n0 + 4 * tn;
    if (n0 + 4 * tn + 4 <= N) {
      *(float4*)cp = make_float4((float)acc[r][0], (float)acc[r][1],
                                 (float)acc[r][2], (float)acc[r][3]);
    } else {
#pragma unroll
      for (int c = 0; c < 4; ++c)
        if (n0 + 4 * tn + c < N) cp[c] = (float)acc[r][c];
    }
  }
}

// ---------------- persistent BiLSTM v3: per-block publish flags, no global barrier ----------------
// Block = (dir, 4-unit slice). Each block's h-slice is produced by exactly one block:
// publish = one plain monotonic sc1 store (flag = #publishes). Readers poll only the
// 25 producer flags of the tile they're about to load (lanes 0-24, one coalesced load).
// Safety: restage of step s requires all 100 flags >= s+1, which is exactly the
// condition making the parity-buffer overwrite (step s write) WAR-safe.
__global__ __launch_bounds__(256, 1) void k_lstm3(const float* __restrict__ xwt,   // [2][128][32][1600] f32
                                                  const float* __restrict__ whh_f, // [1600][400]
                                                  const float* __restrict__ whh_b,
                                                  const int* __restrict__ word_idxs,
                                                  double* __restrict__ hbuf,       // [2][2][400][32] f64
                                                  unsigned* __restrict__ flags,    // [2][128] u32
                                                  float* __restrict__ enc) {
  __shared__ __align__(16) float  Wv[4 * 400 * 4];   // [u][k][g] 25.6 KB
  __shared__ __align__(16) double Sh[3200];          // h tile [100][32] | gpart[4][64][8]
  int bid = blockIdx.x;
  int d = bid / 100, slice = bid - d * 100;
  const float* whh = d ? whh_b : whh_f;
  const float* xwd = xwt + (size_t)d * SEQL * 32 * G4;
  unsigned* flg = flags + (size_t)d * 128;
  int t = threadIdx.x;

  // one-time: stage Whh rows for our 4 units x 4 gates into LDS (interleaved [u][k][g])
  for (int p = 0; p < 16; ++p) {
    int u = p >> 2, g = p & 3;
    const float* src = whh + (size_t)(g * 400 + slice * 4 + u) * 400;
    for (int k = t; k < 400; k += 256) Wv[(u * 400 + k) * 4 + g] = src[k];
  }
  double cst = 0.0;
  int ub = t >> 5, bb = t & 31;          // updater mapping (t<128)
  int kglob = slice * 4 + ub;
  if (t < 128)
    astore(&hbuf[((size_t)1 * 2 + d) * 12800 + (size_t)kglob * 32 + bb], 0.0);
  __syncthreads();                        // drain vmcnt (h init visible)
  if (t == 0) afstore(&flg[slice], 1u);   // publish #1 (initial h)

  int slot = t & 63, kp = t >> 6;
  int su = slot >> 4, sb2 = (slot & 15) * 2;

  for (int s = 0; s < SEQL; ++s) {
    int l = d ? (SEQL - 1 - s) : s;
    int rp = (s + 1) & 1, wp = s & 1;
    const double* hr = hbuf + ((size_t)rp * 2 + d) * 12800;
    unsigned need = (unsigned)(s + 1);

    // prefetch (off critical path): xw gates, hold, mask
    float xw0 = 0.f, xw1 = 0.f, xw2 = 0.f, xw3 = 0.f;
    double holdv = 0.0;
    bool m = false;
    if (t < 128) {
      const float* xp = xwd + ((size_t)l * 32 + bb) * G4 + kglob;
      xw0 = xp[0]; xw1 = xp[400]; xw2 = xp[800]; xw3 = xp[1200];
      holdv = aload(&hr[(size_t)kglob * 32 + bb]);   // own block's prior write
      m = word_idxs[bb * SEQL + l] > 0;
    }

    double acc[8];
#pragma unroll
    for (int z = 0; z < 8; ++z) acc[z] = 0.0;

    for (int kt = 0; kt < 4; ++kt) {
      // per-wave poll of this tile's 25 producer blocks
      {
        bool mine = slot < 25;
        while (true) {
          unsigned v = mine ? afload(&flg[kt * 25 + slot]) : 0xFFFFFFFFu;
          if (__ballot(v < need) == 0ull) break;
          __builtin_amdgcn_s_sleep(1);
        }
      }
      __syncthreads();   // prev tile consumption done (Sh free)
      for (int i = t; i < 3200; i += 256) Sh[i] = aload(&hr[kt * 3200 + i]);
      __syncthreads();
#pragma unroll
      for (int kk = 0; kk < 25; ++kk) {
        int klocal = kk * 4 + kp;
        double2 hp = *(const double2*)&Sh[klocal * 32 + sb2];
        float4 w4 = *(const float4*)&Wv[((size_t)su * 400 + kt * 100 + klocal) * 4];
        acc[0] = fma((double)w4.x, hp.x, acc[0]);
        acc[1] = fma((double)w4.x, hp.y, acc[1]);
        acc[2] = fma((double)w4.y, hp.x, acc[2]);
        acc[3] = fma((double)w4.y, hp.y, acc[3]);
        acc[4] = fma((double)w4.z, hp.x, acc[4]);
        acc[5] = fma((double)w4.z, hp.y, acc[5]);
        acc[6] = fma((double)w4.w, hp.x, acc[6]);
        acc[7] = fma((double)w4.w, hp.y, acc[7]);
      }
    }
    __syncthreads();
    {
      double* gp = Sh + ((size_t)kp * 64 + slot) * 8;
#pragma unroll
      for (int z = 0; z < 8; ++z) gp[z] = acc[z];
    }
    __syncthreads();
    if (t < 128) {
      int slot2 = ub * 16 + (bb >> 1), bbit = bb & 1;
      double g4v[4];
#pragma unroll
      for (int g = 0; g < 4; ++g) {
        double sum = Sh[((size_t)0 * 64 + slot2) * 8 + g * 2 + bbit]
                   + Sh[((size_t)1 * 64 + slot2) * 8 + g * 2 + bbit]
                   + Sh[((size_t)2 * 64 + slot2) * 8 + g * 2 + bbit]
                   + Sh[((size_t)3 * 64 + slot2) * 8 + g * 2 + bbit];
        g4v[g] = sum;
      }
      g4v[0] += (double)xw0; g4v[1] += (double)xw1;
      g4v[2] += (double)xw2; g4v[3] += (double)xw3;
      double si = 1.0 / (1.0 + exp(-g4v[0]));
      double sf = 1.0 / (1.0 + exp(-g4v[1]));
      double so = 1.0 / (1.0 + exp(-g4v[3]));
      double cn = sf * cst + si * tanh(g4v[2]);
      double hn = so * tanh(cn);
      double hw = m ? hn : holdv;
      cst = m ? cn : cst;
      astore(&hbuf[((size_t)wp * 2 + d) * 12800 + (size_t)kglob * 32 + bb], hw);
      enc[((size_t)bb * SEQL + l) * 800 + d * 400 + kglob] = m ? (float)hn : 0.f;
    }
    __syncthreads();                          // drain vmcnt: h stores visible
    if (t == 0) afstore(&flg[slice], (unsigned)(s + 2));   // publish
  }
}

// ---------------- stage 2: score + argmax per (b,x), emits sort keys ----------------
__global__ __launch_bounds__(128) void k_stage2(const float* __restrict__ U,
                                                const float* __restrict__ y1T,
                                                const int* __restrict__ labels,
                                                unsigned long long* __restrict__ keys) {
  __shared__ double Ur[4644];
  int bx = blockIdx.x;
  int b = bx >> 7, x = bx & 127;
  const float* Urow = U + (size_t)bx * 4644;
  for (int i = threadIdx.x; i < 4644; i += 128) Ur[i] = (double)Urow[i];
  __syncthreads();
  int y = threadIdx.x;
  double acc[9];
#pragma unroll
  for (int o = 0; o < 9; ++o) acc[o] = 0.0;
  const float* yb = y1T + (size_t)b * 513 * 128 + y;
  for (int j = 0; j < 513; ++j) {
    double yv = (double)yb[(size_t)j * 128];
#pragma unroll
    for (int o = 0; o < 9; ++o) acc[o] = fma(Ur[o * 516 + j], yv, acc[o]);
  }
  double best = acc[0];
  int bi = 0;
#pragma unroll
  for (int o = 1; o < 9; ++o) {
    if (acc[o] > best) { best = acc[o]; bi = o; }
  }
  int fi = x * 128 + y;
  int lab = labels[(size_t)bx * 128 + y];
  bool valid = (bi != 1) && (lab > 0);
  unsigned long long key;
  if (valid) {
    unsigned long long u = (unsigned long long)__double_as_longlong(best);
    unsigned long long mm = (u >> 63) ? ~u : (u | 0x8000000000000000ull);
    unsigned long long dm = ~mm;
    key = (dm & ~0x3FFFFull) | ((unsigned long long)(unsigned)fi << 4) |
          (unsigned long long)(unsigned)bi;
  } else {
    key = ~0ull;
  }
  keys[(size_t)b * 16384 + fi] = key;
}

// ---------------- decode helpers ----------------
__device__ __forceinline__ void rangemask(int i, int j,
                                          unsigned long long& r0, unsigned long long& r1) {
  if (i > j) { r0 = 0ull; r1 = 0ull; return; }
  unsigned long long u0, u1;
  if (j >= 64) { u0 = ~0ull; u1 = (j >= 127) ? ~0ull : ((1ull << (j - 63)) - 1ull); }
  else         { u0 = (j == 63) ? ~0ull : ((1ull << (j + 1)) - 1ull); u1 = 0ull; }
  unsigned long long f0, f1;
  if (i >= 64) { f0 = 0ull; f1 = (~0ull) << (i - 64); }
  else         { f0 = (~0ull) << i; f1 = ~0ull; }
  r0 = u0 & f0; r1 = u1 & f1;
}

// ---------------- decode: sort + greedy NMS scan, one block per sentence ----------------
__global__ __launch_bounds__(1024) void k_decode(unsigned long long* __restrict__ keysg,
                                                 int* __restrict__ outp) {
  extern __shared__ unsigned long long lds[];
  int b = blockIdx.x;
  int t = threadIdx.x;
  unsigned long long* kg = keysg + (size_t)b * 16384;
  int* ob = outp + (size_t)b * 16384;

  for (int i = t; i < 16384; i += 1024) ob[i] = 1;
  __syncthreads();

  for (int hhalf = 0; hhalf < 2; ++hhalf) {
    for (int i = t; i < 8192; i += 1024) lds[i] = kg[hhalf * 8192 + i];
    __syncthreads();
    bool desc = (hhalf == 1);
    for (int k = 2; k <= 8192; k <<= 1) {
      for (int j = k >> 1; j > 0; j >>= 1) {
        for (int p = 0; p < 8; ++p) {
          int i = p * 1024 + t;
          int ix = i ^ j;
          if (ix > i) {
            unsigned long long ka = lds[i], kb = lds[ix];
            bool up = (((i & k) == 0) != desc);
            if (up ? (ka > kb) : (ka < kb)) { lds[i] = kb; lds[ix] = ka; }
          }
        }
        __syncthreads();
      }
    }
    for (int i = t; i < 8192; i += 1024) kg[hhalf * 8192 + i] = lds[i];
    __syncthreads();
  }
  for (int i = t; i < 8192; i += 1024) {
    unsigned long long ka = kg[i], kb = kg[i + 8192];
    if (ka > kb) { kg[i] = kb; kg[i + 8192] = ka; }
  }
  __syncthreads();
  for (int hhalf = 0; hhalf < 2; ++hhalf) {
    for (int i = t; i < 8192; i += 1024) lds[i] = kg[hhalf * 8192 + i];
    __syncthreads();
    for (int j = 4096; j > 0; j >>= 1) {
      for (int p = 0; p < 8; ++p) {
        int i = p * 1024 + t;
        int ix = i ^ j;
        if (ix > i) {
          unsigned long long ka = lds[i], kb = lds[ix];
          if (ka > kb) { lds[i] = kb; lds[ix] = ka; }
        }
      }
      __syncthreads();
    }
    for (int i = t; i < 8192; i += 1024) kg[hhalf * 8192 + i] = lds[i];
    __syncthreads();
  }

  if (t < 64) {
    const int lane = t;
    unsigned long long s0 = 0, s1 = 0, in0 = 0, in1 = 0;
    for (int base = 0; base < 16384; base += 64) {
      unsigned long long key = kg[base + lane];
      bool valid = (key != ~0ull);
      if (__ballot(valid) == 0ull) break;
      int fi = (int)((key >> 4) & 0x3FFFull);
      int ci = fi >> 7, cj = fi & 127, ca = (int)(key & 15ull);
      bool alive = valid;
      while (true) {
        bool conflict = false;
        {
          unsigned long long r0, r1;
          rangemask(ci, cj, r0, r1);
          if (((r0 & s0) | (r1 & s1)) != 0ull) conflict = true;
          unsigned long long ib = (ci < 64) ? (in0 >> ci) : (in1 >> (ci - 64));
          if (ib & 1ull) conflict = true;
        }
        unsigned long long elig = __ballot(alive && !conflict);
        if (elig == 0ull) break;
        int w = __ffsll((long long)elig) - 1;
        int wi = __shfl(ci, w), wj = __shfl(cj, w);
        if (lane == w) ob[fi] = ca;
        unsigned long long r0, r1;
        rangemask(wi, wj, r0, r1);
        in0 |= r0; in1 |= r1;
        if (wi < 64) s0 |= (1ull << wi); else s1 |= (1ull << (wi - 64));
        alive = alive && (lane > w);
      }
    }
  }
}

extern "C" void kernel_launch(void* const* d_in, const int* in_sizes, int n_in,
                              void* d_out, int out_size, void* d_ws, size_t ws_size,
                              hipStream_t stream) {
  const int*   word_idxs = (const int*)d_in[0];
  const int*   labels    = (const int*)d_in[1];
  const float* word_emb  = (const float*)d_in[2];
  const float* Wih_f = (const float*)d_in[3];
  const float* Whh_f = (const float*)d_in[4];
  const float* bih_f = (const float*)d_in[5];
  const float* bhh_f = (const float*)d_in[6];
  const float* Wih_b = (const float*)d_in[7];
  const float* Whh_b = (const float*)d_in[8];
  const float* bih_b = (const float*)d_in[9];
  const float* bhh_b = (const float*)d_in[10];
  const float* W_start = (const float*)d_in[11];
  const float* b_start = (const float*)d_in[12];
  const float* W_end   = (const float*)d_in[13];
  const float* b_end   = (const float*)d_in[14];
  const float* W_bi    = (const float*)d_in[15];

  char* ws = (char*)d_ws;
  float* x    = (float*)(ws + OFF_X);
  double* hbuf = (double*)(ws + OFF_HBUF);
  unsigned* flags = (unsigned*)(ws + OFF_FLG);
  float* XWt  = (float*)(ws + OFF_XW);
  float* he   = (float*)(ws + OFF_HE);
  float* enc  = (float*)(ws + OFF_ENC);
  float* U    = (float*)(ws + OFF_U);
  float* x1   = (float*)(ws + OFF_X1);
  float* y1T  = (float*)(ws + OFF_Y1T);
  float* Wbp  = (float*)(ws + OFF_WBP);
  unsigned long long* keys = (unsigned long long*)(ws + OFF_KEYS);
  int* outp = (int*)d_out;

  // 1. embedding gather
  k_gather<<<4096, 256, 0, stream>>>(word_idxs, word_emb, x);
  // 2. input-gate GEMMs, bias folded, stored coalesced as XWt[d][l][b][1600]
  dim3 g2(64, 25);
  k_gemm_nt<<<g2, 256, 0, stream>>>(x, EMBD, Wih_f, EMBD, bih_f, bhh_f,
                                    XWt, 0, 4096, G4, EMBD, 2);
  k_gemm_nt<<<g2, 256, 0, stream>>>(x, EMBD, Wih_b, EMBD, bih_b, bhh_b,
                                    XWt + (size_t)SEQL * 32 * G4, 0, 4096, G4, EMBD, 2);
  // 3. flags zero (x region now dead), then persistent LSTM (flag-synced)
  hipMemsetAsync(ws + OFF_FLG, 0, 4096, stream);
  k_lstm3<<<NBLK, 256, 0, stream>>>(XWt, Whh_f, Whh_b, word_idxs, hbuf, flags, enc);
  // 4. projections: x1 (coalesced) and he (coalesced) -> y1T via LDS transpose
  dim3 g4(64, 8);
  k_gemm_nt<<<g4, 256, 0, stream>>>(enc, 800, W_start, 800, b_start, nullptr,
                                    x1, 516, 4096, FF, 800, 0);
  k_gemm_nt<<<g4, 256, 0, stream>>>(enc, 800, W_end, 800, b_end, nullptr,
                                    he, 512, 4096, FF, 800, 0);
  dim3 gt(16, 4, 32);
  k_y1t<<<gt, 256, 0, stream>>>(he, y1T);
  k_ones<<<32, 256, 0, stream>>>(x1, y1T);
  // 5. biaffine stage 1: U[b,x][o][j] = sum_i x1[b,x,i] W[o,i,j]
  k_wbpad<<<(9 * 513 * 516 + 255) / 256, 256, 0, stream>>>(W_bi, Wbp);
  dim3 g5(64, 9, 9);
  k_gemm_nn<<<g5, 256, 0, stream>>>(x1, 516, Wbp, 516, (size_t)513 * 516,
                                    U, 4644, 4096, 513, 513);
  // 6. stage 2 + argmax + key build
  k_stage2<<<4096, 128, 0, stream>>>(U, y1T, labels, keys);
  // 7. sort + greedy NMS decode
  k_decode<<<32, 1024, 65536, stream>>>(keys, outp);
}